// Round 1
// baseline (642.852 us; speedup 1.0000x reference)
//
#include <hip/hip_runtime.h>
#include <math.h>

#define BB 4
#define HH 64
#define WW 64
#define CC 256
#define NHEADS 8
#define DD 32
#define NN 4096   // H*W
#define MM 1024   // (H/2)*(W/2)
#define ATTN_SCALE 0.17677669529663687f
#define LN_EPS 1e-6f

// ---------------------------------------------------------------------------
// 1) depthwise 3x3, stride 1, pad 1.  x:(B,N,C) -> out:(B,N,C)
__global__ __launch_bounds__(256) void dwconv_kernel(
    const float* __restrict__ x, const float* __restrict__ w,
    const float* __restrict__ bias, float* __restrict__ out) {
  int c = threadIdx.x;            // 0..255
  int n = blockIdx.x;             // 0..4095
  int b = blockIdx.y;
  int y = n >> 6, xx = n & 63;
  const float* xb = x + (size_t)b * NN * CC + c;
  float acc = bias[c];
#pragma unroll
  for (int dy = 0; dy < 3; ++dy) {
    int iy = y + dy - 1;
    if (iy < 0 || iy >= HH) continue;
#pragma unroll
    for (int dx = 0; dx < 3; ++dx) {
      int ix = xx + dx - 1;
      if (ix < 0 || ix >= WW) continue;
      acc += xb[(size_t)(iy * WW + ix) * CC] * w[c * 9 + dy * 3 + dx];
    }
  }
  out[((size_t)b * NN + n) * CC + c] = acc;
}

// ---------------------------------------------------------------------------
// 2) depthwise 3x3 stride 2 pad 1 + LayerNorm over C.  x:(B,N,C) -> out:(B,M,C)
__global__ __launch_bounds__(256) void srln_kernel(
    const float* __restrict__ x, const float* __restrict__ w,
    const float* __restrict__ g, const float* __restrict__ beta,
    float* __restrict__ out) {
  int c = threadIdx.x;
  int m = blockIdx.x;             // 0..1023
  int b = blockIdx.y;
  int my = m >> 5, mx = m & 31;
  const float* xb = x + (size_t)b * NN * CC + c;
  float acc = 0.f;
#pragma unroll
  for (int dy = 0; dy < 3; ++dy) {
    int iy = 2 * my + dy - 1;
    if (iy < 0 || iy >= HH) continue;
#pragma unroll
    for (int dx = 0; dx < 3; ++dx) {
      int ix = 2 * mx + dx - 1;
      if (ix < 0 || ix >= WW) continue;
      acc += xb[(size_t)(iy * WW + ix) * CC] * w[c * 9 + dy * 3 + dx];
    }
  }
  __shared__ float s1[256];
  __shared__ float s2[256];
  s1[c] = acc;
  s2[c] = acc * acc;
  __syncthreads();
  for (int s = 128; s > 0; s >>= 1) {
    if (c < s) { s1[c] += s1[c + s]; s2[c] += s2[c + s]; }
    __syncthreads();
  }
  float mu = s1[0] * (1.f / 256.f);
  float var = s2[0] * (1.f / 256.f) - mu * mu;
  float yv = (acc - mu) * rsqrtf(var + LN_EPS) * g[c] + beta[c];
  out[((size_t)b * MM + m) * CC + c] = yv;
}

// ---------------------------------------------------------------------------
// 3) generic GEMM: out[r, co] = bias[co] + sum_ci A[r,ci] * W[co,ci]
//    A: rows x 256 (rows = grid.x*64), W: cols x 256, out: rows x cols
__global__ __launch_bounds__(256) void gemm_bias_kernel(
    const float* __restrict__ A, const float* __restrict__ W,
    const float* __restrict__ bias, float* __restrict__ out, int cols) {
  __shared__ float sA[64][65];
  __shared__ float sW[64][65];
  int t = threadIdx.x;
  int tx = t & 15, ty = t >> 4;
  int r0 = blockIdx.x * 64, c0 = blockIdx.y * 64;
  float acc[4][4] = {};
  for (int kc = 0; kc < 256; kc += 64) {
#pragma unroll
    for (int p = 0; p < 4; ++p) {
      int q = p * 256 + t;
      int row = q >> 4, k4 = (q & 15) * 4;
      float4 va = *reinterpret_cast<const float4*>(&A[((size_t)(r0 + row)) * 256 + kc + k4]);
      sA[row][k4 + 0] = va.x; sA[row][k4 + 1] = va.y;
      sA[row][k4 + 2] = va.z; sA[row][k4 + 3] = va.w;
      float4 vw = *reinterpret_cast<const float4*>(&W[((size_t)(c0 + row)) * 256 + kc + k4]);
      sW[row][k4 + 0] = vw.x; sW[row][k4 + 1] = vw.y;
      sW[row][k4 + 2] = vw.z; sW[row][k4 + 3] = vw.w;
    }
    __syncthreads();
#pragma unroll 16
    for (int k = 0; k < 64; ++k) {
      float a[4], bb[4];
#pragma unroll
      for (int i = 0; i < 4; ++i) a[i] = sA[ty * 4 + i][k];
#pragma unroll
      for (int j = 0; j < 4; ++j) bb[j] = sW[tx * 4 + j][k];
#pragma unroll
      for (int i = 0; i < 4; ++i)
#pragma unroll
        for (int j = 0; j < 4; ++j) acc[i][j] += a[i] * bb[j];
    }
    __syncthreads();
  }
#pragma unroll
  for (int i = 0; i < 4; ++i)
#pragma unroll
    for (int j = 0; j < 4; ++j)
      out[((size_t)(r0 + ty * 4 + i)) * cols + c0 + tx * 4 + j] =
          acc[i][j] + bias[c0 + tx * 4 + j];
}

// ---------------------------------------------------------------------------
// 4) flash-style attention.
//    q2:(B,N,C) with q[b,h,n,d] = q2[b,n,h*32+d]
//    kv:(B,M,512) with k = kv[...,h*32+d], v = kv[...,256+h*32+d]
//    aout:(B,N,C)
__global__ __launch_bounds__(256) void attn_kernel(
    const float* __restrict__ q2, const float* __restrict__ kv,
    float* __restrict__ aout) {
  __shared__ float sQ[64][33];
  __shared__ float sK[64][33];
  __shared__ float sV[64][33];
  __shared__ float sP[64][65];
  int t = threadIdx.x;
  int b = blockIdx.x >> 3, h = blockIdx.x & 7;
  int qt = blockIdx.y;

  const float* qbase = q2 + ((size_t)b * NN + qt * 64) * CC + h * DD;
  for (int i = t; i < 64 * 32; i += 256) {
    int r = i >> 5, d = i & 31;
    sQ[r][d] = qbase[(size_t)r * CC + d];
  }

  int rx = t >> 4;   // row group 0..15 (rows rx*4+i)
  int mx = t & 15;   // score col group / PV d group

  float m_run[4], l_run[4], o[4][2];
#pragma unroll
  for (int i = 0; i < 4; ++i) {
    m_run[i] = -INFINITY; l_run[i] = 0.f; o[i][0] = 0.f; o[i][1] = 0.f;
  }

  const float* kvb = kv + (size_t)b * MM * 512 + h * DD;

  for (int mc = 0; mc < 16; ++mc) {
    int m0 = mc * 64;
    for (int i = t; i < 64 * 32; i += 256) {
      int m = i >> 5, d = i & 31;
      const float* rowp = kvb + (size_t)(m0 + m) * 512;
      sK[m][d] = rowp[d];
      sV[m][d] = rowp[256 + d];
    }
    __syncthreads();

    // scores: rows rx*4+i, cols mx*4+j  (64x64x32 GEMM, 4x4 microtile)
    float sc[4][4];
#pragma unroll
    for (int i = 0; i < 4; ++i)
#pragma unroll
      for (int j = 0; j < 4; ++j) sc[i][j] = 0.f;
#pragma unroll 4
    for (int d = 0; d < 32; ++d) {
      float a[4], bb[4];
#pragma unroll
      for (int i = 0; i < 4; ++i) a[i] = sQ[rx * 4 + i][d];
#pragma unroll
      for (int j = 0; j < 4; ++j) bb[j] = sK[mx * 4 + j][d];
#pragma unroll
      for (int i = 0; i < 4; ++i)
#pragma unroll
        for (int j = 0; j < 4; ++j) sc[i][j] += a[i] * bb[j];
    }

    // online softmax per row (16 lanes per row share via shuffles)
#pragma unroll
    for (int i = 0; i < 4; ++i) {
      float cm = sc[i][0];
#pragma unroll
      for (int j = 1; j < 4; ++j) cm = fmaxf(cm, sc[i][j]);
      cm = fmaxf(cm, __shfl_xor(cm, 1));
      cm = fmaxf(cm, __shfl_xor(cm, 2));
      cm = fmaxf(cm, __shfl_xor(cm, 4));
      cm = fmaxf(cm, __shfl_xor(cm, 8));
      cm *= ATTN_SCALE;
      float nm = fmaxf(m_run[i], cm);
      float alpha = __expf(m_run[i] - nm);
      float cs = 0.f;
#pragma unroll
      for (int j = 0; j < 4; ++j) {
        float p = __expf(sc[i][j] * ATTN_SCALE - nm);
        sP[rx * 4 + i][mx * 4 + j] = p;
        cs += p;
      }
      cs += __shfl_xor(cs, 1);
      cs += __shfl_xor(cs, 2);
      cs += __shfl_xor(cs, 4);
      cs += __shfl_xor(cs, 8);
      l_run[i] = l_run[i] * alpha + cs;
      m_run[i] = nm;
      o[i][0] *= alpha;
      o[i][1] *= alpha;
    }
    __syncthreads();

    // PV: o[rows rx*4+i][d = mx*2+dd] += P * V
#pragma unroll 4
    for (int m = 0; m < 64; ++m) {
      float v0 = sV[m][mx * 2 + 0];
      float v1 = sV[m][mx * 2 + 1];
#pragma unroll
      for (int i = 0; i < 4; ++i) {
        float p = sP[rx * 4 + i][m];
        o[i][0] += p * v0;
        o[i][1] += p * v1;
      }
    }
    __syncthreads();
  }

  float* ob = aout + ((size_t)b * NN + qt * 64) * CC + h * DD;
#pragma unroll
  for (int i = 0; i < 4; ++i) {
    float inv = 1.f / l_run[i];
    ob[(size_t)(rx * 4 + i) * CC + mx * 2 + 0] = o[i][0] * inv;
    ob[(size_t)(rx * 4 + i) * CC + mx * 2 + 1] = o[i][1] * inv;
  }
}

// ---------------------------------------------------------------------------
extern "C" void kernel_launch(void* const* d_in, const int* in_sizes, int n_in,
                              void* d_out, int out_size, void* d_ws, size_t ws_size,
                              hipStream_t stream) {
  const float* x      = (const float*)d_in[0];
  const float* dw_w   = (const float*)d_in[1];
  const float* dw_b   = (const float*)d_in[2];
  const float* pw_w   = (const float*)d_in[3];
  const float* pw_b   = (const float*)d_in[4];
  const float* sr_w   = (const float*)d_in[5];
  const float* ln_g   = (const float*)d_in[6];
  const float* ln_b   = (const float*)d_in[7];
  const float* kv_w   = (const float*)d_in[8];
  const float* kv_b   = (const float*)d_in[9];
  const float* proj_w = (const float*)d_in[10];
  const float* proj_b = (const float*)d_in[11];
  float* out = (float*)d_out;

  float* ws = (float*)d_ws;
  float* q1    = ws;                 // B*N*C  (reused as attention output)
  float* q2    = ws + 4194304;       // B*N*C
  float* xsr   = ws + 8388608;       // B*M*C
  float* kvbuf = ws + 9437184;       // B*M*2C
  // total = 11,534,336 floats = 46.1 MB

  dwconv_kernel<<<dim3(NN, BB), 256, 0, stream>>>(x, dw_w, dw_b, q1);
  gemm_bias_kernel<<<dim3(256, 4), 256, 0, stream>>>(q1, pw_w, pw_b, q2, 256);
  srln_kernel<<<dim3(MM, BB), 256, 0, stream>>>(x, sr_w, ln_g, ln_b, xsr);
  gemm_bias_kernel<<<dim3(64, 8), 256, 0, stream>>>(xsr, kv_w, kv_b, kvbuf, 512);
  attn_kernel<<<dim3(BB * NHEADS, NN / 64), 256, 0, stream>>>(q2, kvbuf, q1);
  gemm_bias_kernel<<<dim3(256, 4), 256, 0, stream>>>(q1, proj_w, proj_b, out, 256);
}

// Round 2
// 292.709 us; speedup vs baseline: 2.1962x; 2.1962x over previous
//
#include <hip/hip_runtime.h>
#include <math.h>

#define BB 4
#define HH 64
#define WW 64
#define CC 256
#define NHEADS 8
#define DD 32
#define NN 4096   // H*W
#define MM 1024   // (H/2)*(W/2)
#define ATTN_SCALE 0.17677669529663687f
#define LN_EPS 1e-6f

typedef __attribute__((ext_vector_type(8)))  short short8;
typedef __attribute__((ext_vector_type(4)))  short short4v;
typedef __attribute__((ext_vector_type(16))) float f32x16;

__device__ __forceinline__ ushort f2bf(float f) {
  unsigned u = __builtin_bit_cast(unsigned, f);
  u += 0x7fffu + ((u >> 16) & 1u);   // RNE
  return (ushort)(u >> 16);
}

// ---------------------------------------------------------------------------
// 1) depthwise 3x3, stride 1, pad 1.  x:(B,N,C) -> out:(B,N,C)
__global__ __launch_bounds__(256) void dwconv_kernel(
    const float* __restrict__ x, const float* __restrict__ w,
    const float* __restrict__ bias, float* __restrict__ out) {
  int c = threadIdx.x;
  int n = blockIdx.x;
  int b = blockIdx.y;
  int y = n >> 6, xx = n & 63;
  const float* xb = x + (size_t)b * NN * CC + c;
  float acc = bias[c];
#pragma unroll
  for (int dy = 0; dy < 3; ++dy) {
    int iy = y + dy - 1;
    if (iy < 0 || iy >= HH) continue;
#pragma unroll
    for (int dx = 0; dx < 3; ++dx) {
      int ix = xx + dx - 1;
      if (ix < 0 || ix >= WW) continue;
      acc += xb[(size_t)(iy * WW + ix) * CC] * w[c * 9 + dy * 3 + dx];
    }
  }
  out[((size_t)b * NN + n) * CC + c] = acc;
}

// ---------------------------------------------------------------------------
// 2) depthwise 3x3 stride 2 pad 1 + LayerNorm over C.  x:(B,N,C) -> out:(B,M,C)
__global__ __launch_bounds__(256) void srln_kernel(
    const float* __restrict__ x, const float* __restrict__ w,
    const float* __restrict__ g, const float* __restrict__ beta,
    float* __restrict__ out) {
  int c = threadIdx.x;
  int m = blockIdx.x;
  int b = blockIdx.y;
  int my = m >> 5, mx = m & 31;
  const float* xb = x + (size_t)b * NN * CC + c;
  float acc = 0.f;
#pragma unroll
  for (int dy = 0; dy < 3; ++dy) {
    int iy = 2 * my + dy - 1;
    if (iy < 0 || iy >= HH) continue;
#pragma unroll
    for (int dx = 0; dx < 3; ++dx) {
      int ix = 2 * mx + dx - 1;
      if (ix < 0 || ix >= WW) continue;
      acc += xb[(size_t)(iy * WW + ix) * CC] * w[c * 9 + dy * 3 + dx];
    }
  }
  __shared__ float s1[256];
  __shared__ float s2[256];
  s1[c] = acc;
  s2[c] = acc * acc;
  __syncthreads();
  for (int s = 128; s > 0; s >>= 1) {
    if (c < s) { s1[c] += s1[c + s]; s2[c] += s2[c + s]; }
    __syncthreads();
  }
  float mu = s1[0] * (1.f / 256.f);
  float var = s2[0] * (1.f / 256.f) - mu * mu;
  float yv = (acc - mu) * rsqrtf(var + LN_EPS) * g[c] + beta[c];
  out[((size_t)b * MM + m) * CC + c] = yv;
}

// ---------------------------------------------------------------------------
// 3) generic fp32 GEMM: out[r,co] = bias[co] + sum_ci A[r,ci]*W[co,ci]
__global__ __launch_bounds__(256) void gemm_bias_kernel(
    const float* __restrict__ A, const float* __restrict__ W,
    const float* __restrict__ bias, float* __restrict__ out, int cols) {
  __shared__ float sA[64][65];
  __shared__ float sW[64][65];
  int t = threadIdx.x;
  int tx = t & 15, ty = t >> 4;
  int r0 = blockIdx.x * 64, c0 = blockIdx.y * 64;
  float acc[4][4] = {};
  for (int kc = 0; kc < 256; kc += 64) {
#pragma unroll
    for (int p = 0; p < 4; ++p) {
      int q = p * 256 + t;
      int row = q >> 4, k4 = (q & 15) * 4;
      float4 va = *reinterpret_cast<const float4*>(&A[((size_t)(r0 + row)) * 256 + kc + k4]);
      sA[row][k4 + 0] = va.x; sA[row][k4 + 1] = va.y;
      sA[row][k4 + 2] = va.z; sA[row][k4 + 3] = va.w;
      float4 vw = *reinterpret_cast<const float4*>(&W[((size_t)(c0 + row)) * 256 + kc + k4]);
      sW[row][k4 + 0] = vw.x; sW[row][k4 + 1] = vw.y;
      sW[row][k4 + 2] = vw.z; sW[row][k4 + 3] = vw.w;
    }
    __syncthreads();
#pragma unroll 16
    for (int k = 0; k < 64; ++k) {
      float a[4], bb[4];
#pragma unroll
      for (int i = 0; i < 4; ++i) a[i] = sA[ty * 4 + i][k];
#pragma unroll
      for (int j = 0; j < 4; ++j) bb[j] = sW[tx * 4 + j][k];
#pragma unroll
      for (int i = 0; i < 4; ++i)
#pragma unroll
        for (int j = 0; j < 4; ++j) acc[i][j] += a[i] * bb[j];
    }
    __syncthreads();
  }
#pragma unroll
  for (int i = 0; i < 4; ++i)
#pragma unroll
    for (int j = 0; j < 4; ++j)
      out[((size_t)(r0 + ty * 4 + i)) * cols + c0 + tx * 4 + j] =
          acc[i][j] + bias[c0 + tx * 4 + j];
}

// ---------------------------------------------------------------------------
// 4a) pack q2 (B,N,256) fp32 -> qB bf16 [b*8+h][n][d]
__global__ __launch_bounds__(256) void pack_q(const float* __restrict__ q2,
                                              ushort* __restrict__ qB) {
  size_t i = ((size_t)blockIdx.x * 256 + threadIdx.x) * 4;
  float4 v = *reinterpret_cast<const float4*>(q2 + i);
  int c = (int)(i & 255);
  size_t n = (i >> 8) & 4095;
  size_t b = i >> 20;
  int h = c >> 5, d = c & 31;
  short4v pk;
  pk[0] = (short)f2bf(v.x); pk[1] = (short)f2bf(v.y);
  pk[2] = (short)f2bf(v.z); pk[3] = (short)f2bf(v.w);
  *reinterpret_cast<short4v*>(qB + (((b * 8 + h) * NN + n) * DD + d)) = pk;
}

// 4b) pack kv (B*M,512) fp32 -> kB bf16 [bh][m][32], vT bf16 [bh][d][1024]
__global__ __launch_bounds__(256) void pack_kv(const float* __restrict__ kv,
                                               ushort* __restrict__ kB,
                                               ushort* __restrict__ vT) {
  __shared__ ushort sT[32][72];
  int t = threadIdx.x;
  int m0 = blockIdx.x * 64;
  int bh = blockIdx.y;
  int b = bh >> 3, h = bh & 7;
  int r = t >> 2, c8 = (t & 3) * 8;
  const float* kvrow = kv + ((size_t)(b * MM + m0 + r)) * 512 + h * DD + c8;
  float4 k0 = *reinterpret_cast<const float4*>(kvrow);
  float4 k1 = *reinterpret_cast<const float4*>(kvrow + 4);
  short8 kk;
  kk[0] = (short)f2bf(k0.x); kk[1] = (short)f2bf(k0.y);
  kk[2] = (short)f2bf(k0.z); kk[3] = (short)f2bf(k0.w);
  kk[4] = (short)f2bf(k1.x); kk[5] = (short)f2bf(k1.y);
  kk[6] = (short)f2bf(k1.z); kk[7] = (short)f2bf(k1.w);
  *reinterpret_cast<short8*>(kB + ((size_t)(bh * MM + m0 + r)) * DD + c8) = kk;
  float4 v0 = *reinterpret_cast<const float4*>(kvrow + 256);
  float4 v1 = *reinterpret_cast<const float4*>(kvrow + 260);
  sT[c8 + 0][r] = f2bf(v0.x); sT[c8 + 1][r] = f2bf(v0.y);
  sT[c8 + 2][r] = f2bf(v0.z); sT[c8 + 3][r] = f2bf(v0.w);
  sT[c8 + 4][r] = f2bf(v1.x); sT[c8 + 5][r] = f2bf(v1.y);
  sT[c8 + 6][r] = f2bf(v1.z); sT[c8 + 7][r] = f2bf(v1.w);
  __syncthreads();
  int d = t >> 3, mc = (t & 7) * 8;
  short8 vv = *reinterpret_cast<const short8*>(&sT[d][mc]);
  *reinterpret_cast<short8*>(vT + ((size_t)(bh * DD + d)) * MM + m0 + mc) = vv;
}

// ---------------------------------------------------------------------------
// 5) MFMA flash attention, S^T formulation.
//    S^T = K·Q^T  (A=K chunk, B=Q^T)  -> C/D col = q (lane&31)
//    O^T = V^T·P  (A=V^T,     B=P)    -> C/D col = q (lane&31)
//    Per block: 128 q-rows (4 waves x 32), loop 16 chunks of 64 m.
__global__ __launch_bounds__(256) void attn_mfma(
    const ushort* __restrict__ qB, const ushort* __restrict__ kB,
    const ushort* __restrict__ vT, float* __restrict__ aout) {
  __shared__ ushort sK[64][40];    // m x d  (pad 32->40)
  __shared__ ushort sVt[32][72];   // d x m  (pad 64->72)
  __shared__ ushort sP[128][72];   // q x m  (pad 64->72)
  int t = threadIdx.x;
  int lane = t & 63, w = t >> 6;
  int l31 = lane & 31, half = lane >> 5;
  int bh = blockIdx.x;
  int b = bh >> 3, h = bh & 7;
  int q0 = blockIdx.y * 128;

  // hoisted Q B-frags: B[k=d][n=q], lane holds d = kb*16 + half*8 + j
  const ushort* qrow = qB + ((size_t)bh * NN + q0 + w * 32 + l31) * DD;
  short8 bq0 = *reinterpret_cast<const short8*>(qrow + half * 8);
  short8 bq1 = *reinterpret_cast<const short8*>(qrow + 16 + half * 8);

  float m_run = -INFINITY, l_run = 0.f;
  f32x16 o;
#pragma unroll
  for (int i = 0; i < 16; ++i) o[i] = 0.f;

  const ushort* kbase = kB + (size_t)bh * MM * DD;
  const ushort* vbase = vT + (size_t)bh * DD * MM;

  for (int mc = 0; mc < 16; ++mc) {
    int m0 = mc * 64;
    // ---- stage K chunk (64x32) and V^T chunk (32x64) as bf16 ----
    {
      short8 kv8 = *reinterpret_cast<const short8*>(kbase + (size_t)m0 * DD + t * 8);
      *reinterpret_cast<short8*>(&sK[t >> 2][(t & 3) * 8]) = kv8;
      int d = t >> 3, mcc = (t & 7) * 8;
      short8 vv8 = *reinterpret_cast<const short8*>(vbase + (size_t)d * MM + m0 + mcc);
      *reinterpret_cast<short8*>(&sVt[d][mcc]) = vv8;
    }
    __syncthreads();

    // ---- S^T = K · Q^T : two 32x32 tiles (m 0..31, 32..63) ----
    f32x16 st[2];
#pragma unroll
    for (int tt = 0; tt < 2; ++tt) {
      short8 a0 = *reinterpret_cast<const short8*>(&sK[tt * 32 + l31][half * 8]);
      short8 a1 = *reinterpret_cast<const short8*>(&sK[tt * 32 + l31][16 + half * 8]);
      f32x16 acc;
#pragma unroll
      for (int i = 0; i < 16; ++i) acc[i] = 0.f;
      acc = __builtin_amdgcn_mfma_f32_32x32x16_bf16(a0, bq0, acc, 0, 0, 0);
      acc = __builtin_amdgcn_mfma_f32_32x32x16_bf16(a1, bq1, acc, 0, 0, 0);
      st[tt] = acc;
    }

    // ---- online softmax (per-lane state: q = w*32 + l31) ----
    float cm = -INFINITY;
#pragma unroll
    for (int tt = 0; tt < 2; ++tt)
#pragma unroll
      for (int i = 0; i < 16; ++i) cm = fmaxf(cm, st[tt][i]);
    cm *= ATTN_SCALE;
    cm = fmaxf(cm, __shfl_xor(cm, 32));
    float nm = fmaxf(m_run, cm);
    float alpha = __expf(m_run - nm);
    float cs = 0.f;
#pragma unroll
    for (int tt = 0; tt < 2; ++tt) {
#pragma unroll
      for (int rg = 0; rg < 4; ++rg) {
        short4v pk;
#pragma unroll
        for (int j = 0; j < 4; ++j) {
          float p = __expf(st[tt][rg * 4 + j] * ATTN_SCALE - nm);
          cs += p;
          pk[j] = (short)f2bf(p);
        }
        // m = tt*32 + rg*8 + half*4 + j
        *reinterpret_cast<short4v*>(&sP[w * 32 + l31][tt * 32 + rg * 8 + half * 4]) = pk;
      }
    }
    cs += __shfl_xor(cs, 32);
    l_run = l_run * alpha + cs;
    m_run = nm;
#pragma unroll
    for (int i = 0; i < 16; ++i) o[i] *= alpha;

    // ---- O^T += V^T · P  (sP written/read by same wave: no barrier) ----
#pragma unroll
    for (int kb = 0; kb < 4; ++kb) {
      short8 av = *reinterpret_cast<const short8*>(&sVt[l31][kb * 16 + half * 8]);
      short8 bp = *reinterpret_cast<const short8*>(&sP[w * 32 + l31][kb * 16 + half * 8]);
      o = __builtin_amdgcn_mfma_f32_32x32x16_bf16(av, bp, o, 0, 0, 0);
    }
    __syncthreads();
  }

  // ---- epilogue: out[b][n=q][h*32+d] = o/l ----
  float inv = 1.f / l_run;
  float* ob = aout + ((size_t)b * NN + q0 + w * 32 + l31) * CC + h * DD;
#pragma unroll
  for (int rg = 0; rg < 4; ++rg) {
    float4 v4;
    v4.x = o[rg * 4 + 0] * inv;
    v4.y = o[rg * 4 + 1] * inv;
    v4.z = o[rg * 4 + 2] * inv;
    v4.w = o[rg * 4 + 3] * inv;
    *reinterpret_cast<float4*>(ob + rg * 8 + half * 4) = v4;
  }
}

// ---------------------------------------------------------------------------
extern "C" void kernel_launch(void* const* d_in, const int* in_sizes, int n_in,
                              void* d_out, int out_size, void* d_ws, size_t ws_size,
                              hipStream_t stream) {
  const float* x      = (const float*)d_in[0];
  const float* dw_w   = (const float*)d_in[1];
  const float* dw_b   = (const float*)d_in[2];
  const float* pw_w   = (const float*)d_in[3];
  const float* pw_b   = (const float*)d_in[4];
  const float* sr_w   = (const float*)d_in[5];
  const float* ln_g   = (const float*)d_in[6];
  const float* ln_b   = (const float*)d_in[7];
  const float* kv_w   = (const float*)d_in[8];
  const float* kv_b   = (const float*)d_in[9];
  const float* proj_w = (const float*)d_in[10];
  const float* proj_b = (const float*)d_in[11];
  float* out = (float*)d_out;

  float* ws = (float*)d_ws;
  float*  q1    = ws;                         // 4M floats
  float*  q2    = ws + 4194304;               // 4M floats
  float*  xsr   = ws + 8388608;               // 1M floats
  float*  kvbuf = ws + 9437184;               // 2M floats
  ushort* qBp   = (ushort*)(ws + 11534336);   // 4M bf16 (2M floats)
  ushort* kBp   = (ushort*)(ws + 13631488);   // 1M bf16 (0.5M floats)
  ushort* vTp   = (ushort*)(ws + 14155776);   // 1M bf16 (0.5M floats)
  // total 14,680,064 floats = 58.7 MB

  dwconv_kernel<<<dim3(NN, BB), 256, 0, stream>>>(x, dw_w, dw_b, q1);
  gemm_bias_kernel<<<dim3(256, 4), 256, 0, stream>>>(q1, pw_w, pw_b, q2, 256);
  pack_q<<<dim3(4096), 256, 0, stream>>>(q2, qBp);
  srln_kernel<<<dim3(MM, BB), 256, 0, stream>>>(x, sr_w, ln_g, ln_b, xsr);
  gemm_bias_kernel<<<dim3(64, 8), 256, 0, stream>>>(xsr, kv_w, kv_b, kvbuf, 512);
  pack_kv<<<dim3(16, 32), 256, 0, stream>>>(kvbuf, kBp, vTp);
  attn_mfma<<<dim3(32, 32), 256, 0, stream>>>(qBp, kBp, vTp, q1);
  gemm_bias_kernel<<<dim3(256, 4), 256, 0, stream>>>(q1, proj_w, proj_b, out, 256);
}

// Round 3
// 198.799 us; speedup vs baseline: 3.2337x; 1.4724x over previous
//
#include <hip/hip_runtime.h>
#include <math.h>

#define BB 4
#define HH 64
#define WW 64
#define CC 256
#define NN 4096   // H*W
#define MM 1024   // (H/2)*(W/2)
#define LN_EPS 1e-6f
// ATTN_SCALE * log2(e), folded into q at pack time -> softmax uses exp2 directly
#define SLF (0.17677669529663687f * 1.4426950408889634f)

typedef __attribute__((ext_vector_type(8)))  short short8;
typedef __attribute__((ext_vector_type(16))) float f32x16;

__device__ __forceinline__ ushort f2bf(float f) {
  unsigned u = __builtin_bit_cast(unsigned, f);
  u += 0x7fffu + ((u >> 16) & 1u);   // RNE
  return (ushort)(u >> 16);
}
__device__ __forceinline__ float bf2f(ushort h) {
  unsigned u = ((unsigned)h) << 16;
  return __builtin_bit_cast(float, u);
}
#if __has_builtin(__builtin_amdgcn_exp2f)
#define EXP2F(x) __builtin_amdgcn_exp2f(x)
#else
#define EXP2F(x) exp2f(x)
#endif

// ---------------------------------------------------------------------------
// 1) depthwise 3x3, stride 1, pad 1.  x:(B,N,C) fp32 -> out bf16 (B*N,256)
__global__ __launch_bounds__(256) void dwconv_kernel(
    const float* __restrict__ x, const float* __restrict__ w,
    const float* __restrict__ bias, ushort* __restrict__ out) {
  int c = threadIdx.x;
  int n = blockIdx.x;
  int b = blockIdx.y;
  int y = n >> 6, xx = n & 63;
  const float* xb = x + (size_t)b * NN * CC + c;
  float acc = bias[c];
#pragma unroll
  for (int dy = 0; dy < 3; ++dy) {
    int iy = y + dy - 1;
    if (iy < 0 || iy >= HH) continue;
#pragma unroll
    for (int dx = 0; dx < 3; ++dx) {
      int ix = xx + dx - 1;
      if (ix < 0 || ix >= WW) continue;
      acc += xb[(size_t)(iy * WW + ix) * CC] * w[c * 9 + dy * 3 + dx];
    }
  }
  out[((size_t)b * NN + n) * CC + c] = f2bf(acc);
}

// ---------------------------------------------------------------------------
// 2) depthwise 3x3 stride 2 pad 1 + LayerNorm over C -> bf16 (B*M,256)
__global__ __launch_bounds__(256) void srln_kernel(
    const float* __restrict__ x, const float* __restrict__ w,
    const float* __restrict__ g, const float* __restrict__ beta,
    ushort* __restrict__ out) {
  int c = threadIdx.x;
  int m = blockIdx.x;
  int b = blockIdx.y;
  int my = m >> 5, mx = m & 31;
  const float* xb = x + (size_t)b * NN * CC + c;
  float acc = 0.f;
#pragma unroll
  for (int dy = 0; dy < 3; ++dy) {
    int iy = 2 * my + dy - 1;
    if (iy < 0 || iy >= HH) continue;
#pragma unroll
    for (int dx = 0; dx < 3; ++dx) {
      int ix = 2 * mx + dx - 1;
      if (ix < 0 || ix >= WW) continue;
      acc += xb[(size_t)(iy * WW + ix) * CC] * w[c * 9 + dy * 3 + dx];
    }
  }
  float v1 = acc, v2 = acc * acc;
#pragma unroll
  for (int s = 1; s < 64; s <<= 1) {
    v1 += __shfl_xor(v1, s);
    v2 += __shfl_xor(v2, s);
  }
  __shared__ float r1[4], r2[4];
  int lane = c & 63, wv = c >> 6;
  if (lane == 0) { r1[wv] = v1; r2[wv] = v2; }
  __syncthreads();
  float s1 = r1[0] + r1[1] + r1[2] + r1[3];
  float s2 = r2[0] + r2[1] + r2[2] + r2[3];
  float mu = s1 * (1.f / 256.f);
  float var = s2 * (1.f / 256.f) - mu * mu;
  float yv = (acc - mu) * rsqrtf(var + LN_EPS) * g[c] + beta[c];
  out[((size_t)b * MM + m) * CC + c] = f2bf(yv);
}

// ---------------------------------------------------------------------------
// 3) Unified bf16 MFMA GEMM: out[r,c] = bias[c] + sum_k A[r,k]*W[c,k]
//    Tile 128 rows x 64 cols, 4 waves (wave owns 32 rows x 64 cols = 2 acc).
//    MODE 0: qB epilogue  (bf16, head layout, *SLF folded)
//    MODE 1: kv epilogue  (c<256 -> kB head layout; c>=256 -> vT via swapped
//                          mfma operands, coalesced transposed store)
//    MODE 2: proj, hi/lo split A (A,A2) and W (split in staging), fp32 out
template <int MODE>
__global__ __launch_bounds__(256) void gemm_mfma(
    const ushort* __restrict__ A, const ushort* __restrict__ A2,
    const float* __restrict__ W, const float* __restrict__ bias,
    void* __restrict__ out0, void* __restrict__ out1) {
  extern __shared__ ushort smem[];
  ushort (*sA)[40]  = (ushort(*)[40])smem;                          // 128x40
  ushort (*sW)[40]  = (ushort(*)[40])(smem + 128 * 40);             // 64x40
  ushort (*sA2)[40] = (ushort(*)[40])(smem + 128 * 40 + 64 * 40);   // 128x40
  ushort (*sW2)[40] = (ushort(*)[40])(smem + 2 * 128 * 40 + 64 * 40);

  int t = threadIdx.x;
  int lane = t & 63, w = t >> 6;
  int l31 = lane & 31, half = lane >> 5;
  int r0 = blockIdx.x * 128;
  int c0 = blockIdx.y * 64;
  const bool vmode = (MODE == 1) && (c0 >= 256);

  f32x16 acc[2];
#pragma unroll
  for (int ct = 0; ct < 2; ++ct)
#pragma unroll
    for (int i = 0; i < 16; ++i) acc[ct][i] = 0.f;

  for (int kc = 0; kc < 256; kc += 32) {
    // stage A (128 x 32 bf16)
#pragma unroll
    for (int i = 0; i < 2; ++i) {
      int idx = t + i * 256;
      int row = idx >> 2, kq = (idx & 3) * 8;
      *(short8*)&sA[row][kq] =
          *(const short8*)&A[(size_t)(r0 + row) * 256 + kc + kq];
      if constexpr (MODE == 2)
        *(short8*)&sA2[row][kq] =
            *(const short8*)&A2[(size_t)(r0 + row) * 256 + kc + kq];
    }
    // stage W (64 x 32), fp32 -> bf16 (hi/lo for MODE 2)
    {
      int col = t >> 2, kq = (t & 3) * 8;
      const float* wp = &W[(size_t)(c0 + col) * 256 + kc + kq];
      float4 w0 = *(const float4*)wp;
      float4 w1 = *(const float4*)(wp + 4);
      float vals[8] = {w0.x, w0.y, w0.z, w0.w, w1.x, w1.y, w1.z, w1.w};
      short8 hi;
#pragma unroll
      for (int j = 0; j < 8; ++j) hi[j] = (short)f2bf(vals[j]);
      *(short8*)&sW[col][kq] = hi;
      if constexpr (MODE == 2) {
        short8 lo;
#pragma unroll
        for (int j = 0; j < 8; ++j)
          lo[j] = (short)f2bf(vals[j] - bf2f((ushort)hi[j]));
        *(short8*)&sW2[col][kq] = lo;
      }
    }
    __syncthreads();
#pragma unroll
    for (int ks = 0; ks < 2; ++ks) {
      short8 af = *(const short8*)&sA[w * 32 + l31][ks * 16 + half * 8];
      short8 af2;
      if constexpr (MODE == 2)
        af2 = *(const short8*)&sA2[w * 32 + l31][ks * 16 + half * 8];
#pragma unroll
      for (int ct = 0; ct < 2; ++ct) {
        short8 wf = *(const short8*)&sW[ct * 32 + l31][ks * 16 + half * 8];
        if constexpr (MODE == 2) {
          short8 wf2 = *(const short8*)&sW2[ct * 32 + l31][ks * 16 + half * 8];
          acc[ct] = __builtin_amdgcn_mfma_f32_32x32x16_bf16(af, wf, acc[ct], 0, 0, 0);
          acc[ct] = __builtin_amdgcn_mfma_f32_32x32x16_bf16(af2, wf, acc[ct], 0, 0, 0);
          acc[ct] = __builtin_amdgcn_mfma_f32_32x32x16_bf16(af, wf2, acc[ct], 0, 0, 0);
        } else if (vmode) {
          acc[ct] = __builtin_amdgcn_mfma_f32_32x32x16_bf16(wf, af, acc[ct], 0, 0, 0);
        } else {
          acc[ct] = __builtin_amdgcn_mfma_f32_32x32x16_bf16(af, wf, acc[ct], 0, 0, 0);
        }
      }
    }
    __syncthreads();
  }

  // epilogue
#pragma unroll
  for (int ct = 0; ct < 2; ++ct) {
#pragma unroll
    for (int i = 0; i < 16; ++i) {
      int rl = (i & 3) + 8 * (i >> 2) + 4 * half;
      if constexpr (MODE == 0) {
        int r = r0 + w * 32 + rl;
        int c = c0 + ct * 32 + l31;
        int b = r >> 12, n = r & 4095;
        int h = c >> 5, d = c & 31;
        float v = (acc[ct][i] + bias[c]) * SLF;
        ((ushort*)out0)[((size_t)(b * 8 + h) * NN + n) * 32 + d] = f2bf(v);
      } else if constexpr (MODE == 1) {
        if (!vmode) {
          int r = r0 + w * 32 + rl;
          int c = c0 + ct * 32 + l31;
          int b = r >> 10, m = r & 1023;
          int h = c >> 5, d = c & 31;
          ((ushort*)out0)[((size_t)(b * 8 + h) * MM + m) * 32 + d] =
              f2bf(acc[ct][i] + bias[c]);
        } else {
          int c = c0 + ct * 32 + rl;        // swapped: rows of D are cols
          int r = r0 + w * 32 + l31;        // cols of D are A-rows (m)
          int b = r >> 10, m = r & 1023;
          int cv = c - 256;
          int h = cv >> 5, d = cv & 31;
          ((ushort*)out1)[((size_t)(b * 8 + h) * 32 + d) * MM + m] =
              f2bf(acc[ct][i] + bias[c]);
        }
      } else {
        int r = r0 + w * 32 + rl;
        int c = c0 + ct * 32 + l31;
        ((float*)out0)[(size_t)r * 256 + c] = acc[ct][i] + bias[c];
      }
    }
  }
}

// ---------------------------------------------------------------------------
// 4) MFMA flash attention (S^T = K·Q^T, O^T = V^T·P), exp2-domain softmax,
//    single-barrier double-buffered K/V staging. Output: hi/lo bf16 planes.
__global__ __launch_bounds__(256, 4) void attn_mfma(
    const ushort* __restrict__ qB, const ushort* __restrict__ kB,
    const ushort* __restrict__ vT, ushort* __restrict__ aH,
    ushort* __restrict__ aL) {
  __shared__ ushort sK[2][64][40];
  __shared__ ushort sVt[2][32][72];
  __shared__ ushort sP[128][72];
  int t = threadIdx.x;
  int lane = t & 63, w = t >> 6;
  int l31 = lane & 31, half = lane >> 5;
  int bh = blockIdx.x;
  int b = bh >> 3, h = bh & 7;
  int q0 = blockIdx.y * 128;

  const ushort* qrow = qB + ((size_t)bh * NN + q0 + w * 32 + l31) * 32;
  short8 bq0 = *(const short8*)(qrow + half * 8);
  short8 bq1 = *(const short8*)(qrow + 16 + half * 8);

  const ushort* kbase = kB + (size_t)bh * MM * 32;
  const ushort* vbase = vT + (size_t)bh * 32 * MM;
  int krow = t >> 2, kq = (t & 3) * 8;
  int vd = t >> 3, vmo = (t & 7) * 8;

  short8 kreg = *(const short8*)&kbase[(size_t)krow * 32 + kq];
  short8 vreg = *(const short8*)&vbase[(size_t)vd * MM + vmo];
  *(short8*)&sK[0][krow][kq] = kreg;
  *(short8*)&sVt[0][vd][vmo] = vreg;

  float m_run = -3.0e38f, l_run = 0.f;
  f32x16 o;
#pragma unroll
  for (int i = 0; i < 16; ++i) o[i] = 0.f;
  __syncthreads();

  for (int mc = 0; mc < 16; ++mc) {
    int cur = mc & 1, nxt = cur ^ 1;
    if (mc < 15) {
      int m0n = (mc + 1) * 64;
      kreg = *(const short8*)&kbase[(size_t)(m0n + krow) * 32 + kq];
      vreg = *(const short8*)&vbase[(size_t)vd * MM + m0n + vmo];
    }
    // S^T = K·Q^T : two 32x32 tiles
    f32x16 st[2];
#pragma unroll
    for (int tt = 0; tt < 2; ++tt) {
      short8 a0 = *(const short8*)&sK[cur][tt * 32 + l31][half * 8];
      short8 a1 = *(const short8*)&sK[cur][tt * 32 + l31][16 + half * 8];
      f32x16 z;
#pragma unroll
      for (int i = 0; i < 16; ++i) z[i] = 0.f;
      z = __builtin_amdgcn_mfma_f32_32x32x16_bf16(a0, bq0, z, 0, 0, 0);
      z = __builtin_amdgcn_mfma_f32_32x32x16_bf16(a1, bq1, z, 0, 0, 0);
      st[tt] = z;
    }

    // online softmax (log2 domain; scale pre-folded into q)
    float cm = st[0][0];
#pragma unroll
    for (int tt = 0; tt < 2; ++tt)
#pragma unroll
      for (int i = 0; i < 16; ++i) cm = fmaxf(cm, st[tt][i]);
    cm = fmaxf(cm, __shfl_xor(cm, 32));
    float nm = fmaxf(m_run, cm);
    float alpha = EXP2F(m_run - nm);
    float cs = 0.f;
#pragma unroll
    for (int tt = 0; tt < 2; ++tt) {
#pragma unroll
      for (int rg = 0; rg < 4; ++rg) {
        float p0 = EXP2F(st[tt][rg * 4 + 0] - nm);
        float p1 = EXP2F(st[tt][rg * 4 + 1] - nm);
        float p2 = EXP2F(st[tt][rg * 4 + 2] - nm);
        float p3 = EXP2F(st[tt][rg * 4 + 3] - nm);
        unsigned u0 = __builtin_bit_cast(unsigned, p0);
        unsigned u1 = __builtin_bit_cast(unsigned, p1);
        unsigned u2 = __builtin_bit_cast(unsigned, p2);
        unsigned u3 = __builtin_bit_cast(unsigned, p3);
        // cs from truncated values -> normalization consistent with stored P
        cs += __builtin_bit_cast(float, u0 & 0xffff0000u);
        cs += __builtin_bit_cast(float, u1 & 0xffff0000u);
        cs += __builtin_bit_cast(float, u2 & 0xffff0000u);
        cs += __builtin_bit_cast(float, u3 & 0xffff0000u);
        uint2 pk;
        pk.x = __builtin_amdgcn_perm(u1, u0, 0x07060302);
        pk.y = __builtin_amdgcn_perm(u3, u2, 0x07060302);
        *(uint2*)&sP[w * 32 + l31][tt * 32 + rg * 8 + half * 4] = pk;
      }
    }
    cs += __shfl_xor(cs, 32);
    l_run = l_run * alpha + cs;
    m_run = nm;
#pragma unroll
    for (int i = 0; i < 16; ++i) o[i] *= alpha;

    // O^T += V^T·P  (sP same-wave: no barrier needed)
#pragma unroll
    for (int kb = 0; kb < 4; ++kb) {
      short8 av = *(const short8*)&sVt[cur][l31][kb * 16 + half * 8];
      short8 bp = *(const short8*)&sP[w * 32 + l31][kb * 16 + half * 8];
      o = __builtin_amdgcn_mfma_f32_32x32x16_bf16(av, bp, o, 0, 0, 0);
    }

    if (mc < 15) {
      *(short8*)&sK[nxt][krow][kq] = kreg;
      *(short8*)&sVt[nxt][vd][vmo] = vreg;
    }
    __syncthreads();
  }

  // epilogue: hi/lo bf16 planes, row-major (B*N, 256)
  float inv = 1.f / l_run;
  size_t rbase = ((size_t)b * NN + q0 + w * 32 + l31) * 256 + h * 32;
#pragma unroll
  for (int rg = 0; rg < 4; ++rg) {
#pragma unroll
    for (int j = 0; j < 4; ++j) {
      float v = o[rg * 4 + j] * inv;
      ushort hi = f2bf(v);
      ushort lo = f2bf(v - bf2f(hi));
      int d = rg * 8 + half * 4 + j;
      aH[rbase + d] = hi;
      aL[rbase + d] = lo;
    }
  }
}

// ---------------------------------------------------------------------------
extern "C" void kernel_launch(void* const* d_in, const int* in_sizes, int n_in,
                              void* d_out, int out_size, void* d_ws, size_t ws_size,
                              hipStream_t stream) {
  const float* x      = (const float*)d_in[0];
  const float* dw_w   = (const float*)d_in[1];
  const float* dw_b   = (const float*)d_in[2];
  const float* pw_w   = (const float*)d_in[3];
  const float* pw_b   = (const float*)d_in[4];
  const float* sr_w   = (const float*)d_in[5];
  const float* ln_g   = (const float*)d_in[6];
  const float* ln_b   = (const float*)d_in[7];
  const float* kv_w   = (const float*)d_in[8];
  const float* kv_b   = (const float*)d_in[9];
  const float* proj_w = (const float*)d_in[10];
  const float* proj_b = (const float*)d_in[11];
  float* out = (float*)d_out;

  char* ws = (char*)d_ws;
  ushort* q1b = (ushort*)(ws);                  // 16384x256 bf16  (8 MB)
  ushort* xsr = (ushort*)(ws + (8u << 20));     // 4096x256        (2 MB)
  ushort* qB  = (ushort*)(ws + (16u << 20));    // 32x4096x32      (8 MB)
  ushort* kBp = (ushort*)(ws + (24u << 20));    // 32x1024x32      (2 MB)
  ushort* vTp = (ushort*)(ws + (26u << 20));    // 32x32x1024      (2 MB)
  ushort* aH  = (ushort*)(ws + (28u << 20));    // 16384x256       (8 MB)
  ushort* aL  = (ushort*)(ws + (36u << 20));    // 16384x256       (8 MB)
  // total 44 MB

  const size_t smem_plain = (128 * 40 + 64 * 40) * sizeof(ushort);
  const size_t smem_proj  = 2 * smem_plain;

  dwconv_kernel<<<dim3(NN, BB), 256, 0, stream>>>(x, dw_w, dw_b, q1b);
  srln_kernel<<<dim3(MM, BB), 256, 0, stream>>>(x, sr_w, ln_g, ln_b, xsr);
  gemm_mfma<0><<<dim3(128, 4), 256, smem_plain, stream>>>(
      q1b, nullptr, pw_w, pw_b, qB, nullptr);
  gemm_mfma<1><<<dim3(32, 8), 256, smem_plain, stream>>>(
      xsr, nullptr, kv_w, kv_b, kBp, vTp);
  attn_mfma<<<dim3(32, 32), 256, 0, stream>>>(qB, kBp, vTp, aH, aL);
  gemm_mfma<2><<<dim3(128, 4), 256, smem_proj, stream>>>(
      aH, aL, proj_w, proj_b, out, nullptr);
}

// Round 4
// 180.081 us; speedup vs baseline: 3.5698x; 1.1039x over previous
//
#include <hip/hip_runtime.h>
#include <math.h>

#define BB 4
#define HH 64
#define WW 64
#define CC 256
#define NN 4096   // H*W
#define MM 1024   // (H/2)*(W/2)
#define LN_EPS 1e-6f
// ATTN_SCALE * log2(e), folded into q at pack time -> softmax uses exp2 directly
#define SLF (0.17677669529663687f * 1.4426950408889634f)

typedef __attribute__((ext_vector_type(8)))  short short8;
typedef __attribute__((ext_vector_type(16))) float f32x16;

__device__ __forceinline__ ushort f2bf(float f) {
  unsigned u = __builtin_bit_cast(unsigned, f);
  u += 0x7fffu + ((u >> 16) & 1u);   // RNE
  return (ushort)(u >> 16);
}
__device__ __forceinline__ float bf2f(ushort h) {
  unsigned u = ((unsigned)h) << 16;
  return __builtin_bit_cast(float, u);
}
#if __has_builtin(__builtin_amdgcn_exp2f)
#define EXP2F(x) __builtin_amdgcn_exp2f(x)
#else
#define EXP2F(x) exp2f(x)
#endif

// ---------------------------------------------------------------------------
// 1) depthwise 3x3, stride 1, pad 1, row-streaming.
//    x:(B,N,C) fp32 -> out bf16 (B*N,256). Block = (row y, half hf), thread=c.
__global__ __launch_bounds__(256) void dwconv_kernel(
    const float* __restrict__ x, const float* __restrict__ w,
    const float* __restrict__ bias, ushort* __restrict__ out) {
  int c = threadIdx.x;
  int y = blockIdx.x >> 1, hf = blockIdx.x & 1;
  int b = blockIdx.y;
  float wr[9];
#pragma unroll
  for (int i = 0; i < 9; ++i) wr[i] = w[c * 9 + i];
  float bi = bias[c];
  const float* xb = x + (size_t)b * NN * CC + c;
  int x0 = hf * 32;
  bool okT = (y > 0), okB = (y < 63);
  // window: rows (T,M,B) x cols (xx-1, xx)
  float a0, a1, a2, b0, b1, b2;
  if (x0 == 0) {
    a0 = a1 = a2 = 0.f;
  } else {
    a0 = okT ? xb[(size_t)((y - 1) * 64 + x0 - 1) * CC] : 0.f;
    a1 = xb[(size_t)(y * 64 + x0 - 1) * CC];
    a2 = okB ? xb[(size_t)((y + 1) * 64 + x0 - 1) * CC] : 0.f;
  }
  b0 = okT ? xb[(size_t)((y - 1) * 64 + x0) * CC] : 0.f;
  b1 = xb[(size_t)(y * 64 + x0) * CC];
  b2 = okB ? xb[(size_t)((y + 1) * 64 + x0) * CC] : 0.f;
  ushort* ob = out + ((size_t)b * NN + y * 64) * CC + c;
#pragma unroll 8
  for (int xx = x0; xx < x0 + 32; ++xx) {
    float c0v, c1v, c2v;
    if (xx < 63) {
      c0v = okT ? xb[(size_t)((y - 1) * 64 + xx + 1) * CC] : 0.f;
      c1v = xb[(size_t)(y * 64 + xx + 1) * CC];
      c2v = okB ? xb[(size_t)((y + 1) * 64 + xx + 1) * CC] : 0.f;
    } else {
      c0v = c1v = c2v = 0.f;
    }
    float acc = bi;
    acc += a0 * wr[0] + b0 * wr[1] + c0v * wr[2];
    acc += a1 * wr[3] + b1 * wr[4] + c1v * wr[5];
    acc += a2 * wr[6] + b2 * wr[7] + c2v * wr[8];
    ob[(size_t)xx * CC] = f2bf(acc);
    a0 = b0; a1 = b1; a2 = b2;
    b0 = c0v; b1 = c1v; b2 = c2v;
  }
}

// ---------------------------------------------------------------------------
// 2) depthwise 3x3 stride 2 pad 1 + LayerNorm over C -> bf16 (B*M,256)
__global__ __launch_bounds__(256) void srln_kernel(
    const float* __restrict__ x, const float* __restrict__ w,
    const float* __restrict__ g, const float* __restrict__ beta,
    ushort* __restrict__ out) {
  int c = threadIdx.x;
  int m = blockIdx.x;
  int b = blockIdx.y;
  int my = m >> 5, mx = m & 31;
  const float* xb = x + (size_t)b * NN * CC + c;
  float acc = 0.f;
#pragma unroll
  for (int dy = 0; dy < 3; ++dy) {
    int iy = 2 * my + dy - 1;
    if (iy < 0 || iy >= HH) continue;
#pragma unroll
    for (int dx = 0; dx < 3; ++dx) {
      int ix = 2 * mx + dx - 1;
      if (ix < 0 || ix >= WW) continue;
      acc += xb[(size_t)(iy * WW + ix) * CC] * w[c * 9 + dy * 3 + dx];
    }
  }
  float v1 = acc, v2 = acc * acc;
#pragma unroll
  for (int s = 1; s < 64; s <<= 1) {
    v1 += __shfl_xor(v1, s);
    v2 += __shfl_xor(v2, s);
  }
  __shared__ float r1[4], r2[4];
  int lane = c & 63, wv = c >> 6;
  if (lane == 0) { r1[wv] = v1; r2[wv] = v2; }
  __syncthreads();
  float s1 = r1[0] + r1[1] + r1[2] + r1[3];
  float s2 = r2[0] + r2[1] + r2[2] + r2[3];
  float mu = s1 * (1.f / 256.f);
  float var = s2 * (1.f / 256.f) - mu * mu;
  float yv = (acc - mu) * rsqrtf(var + LN_EPS) * g[c] + beta[c];
  out[((size_t)b * MM + m) * CC + c] = f2bf(yv);
}

// ---------------------------------------------------------------------------
// 3) Unified bf16 MFMA GEMM, double-buffered single-barrier pipeline.
//    out[r,c] = bias[c] + sum_k A[r,k]*W[c,k].  Tile 128x64, 4 waves.
//    MODE 0: qB epilogue (bf16 head layout, *SLF folded)
//    MODE 1: kv epilogue (c<256 -> kB head layout; c>=256 -> vT transposed
//                         via swapped mfma operands)
//    MODE 2: proj, hi/lo split A (A,A2) and W, fp32 out
template <int MODE>
__global__ __launch_bounds__(256) void gemm_mfma(
    const ushort* __restrict__ A, const ushort* __restrict__ A2,
    const float* __restrict__ W, const float* __restrict__ bias,
    void* __restrict__ out0, void* __restrict__ out1) {
  extern __shared__ ushort smem[];
  constexpr int AS = 128 * 40, WS = 64 * 40;
  constexpr int OA = 0, OW = AS, OA2 = AS + WS, OW2 = 2 * AS + WS;
  constexpr int BUF = (MODE == 2) ? 2 * (AS + WS) : (AS + WS);
  ushort* bf0 = smem;
  ushort* bf1 = smem + BUF;

  int t = threadIdx.x;
  int lane = t & 63, w = t >> 6;
  int l31 = lane & 31, half = lane >> 5;
  int r0 = blockIdx.x * 128;
  int c0 = blockIdx.y * 64;
  const bool vmode = (MODE == 1) && (c0 >= 256);

  int rowA = t >> 2, kq = (t & 3) * 8;   // rowA also = W column (0..63)

  f32x16 acc[2];
#pragma unroll
  for (int ct = 0; ct < 2; ++ct)
#pragma unroll
    for (int i = 0; i < 16; ++i) acc[ct][i] = 0.f;

  short8 ra0, ra1, ra20, ra21;
  float4 rw0, rw1;

  auto prefetch = [&](int kc) {
    ra0 = *(const short8*)&A[(size_t)(r0 + rowA) * 256 + kc + kq];
    ra1 = *(const short8*)&A[(size_t)(r0 + rowA + 64) * 256 + kc + kq];
    const float* wp = &W[(size_t)(c0 + rowA) * 256 + kc + kq];
    rw0 = *(const float4*)wp;
    rw1 = *(const float4*)(wp + 4);
    if constexpr (MODE == 2) {
      ra20 = *(const short8*)&A2[(size_t)(r0 + rowA) * 256 + kc + kq];
      ra21 = *(const short8*)&A2[(size_t)(r0 + rowA + 64) * 256 + kc + kq];
    }
  };

  auto store = [&](ushort* buf) {
    *(short8*)&buf[OA + rowA * 40 + kq] = ra0;
    *(short8*)&buf[OA + (rowA + 64) * 40 + kq] = ra1;
    float vals[8] = {rw0.x, rw0.y, rw0.z, rw0.w, rw1.x, rw1.y, rw1.z, rw1.w};
    short8 hi;
#pragma unroll
    for (int j = 0; j < 8; ++j) hi[j] = (short)f2bf(vals[j]);
    *(short8*)&buf[OW + rowA * 40 + kq] = hi;
    if constexpr (MODE == 2) {
      *(short8*)&buf[OA2 + rowA * 40 + kq] = ra20;
      *(short8*)&buf[OA2 + (rowA + 64) * 40 + kq] = ra21;
      short8 lo;
#pragma unroll
      for (int j = 0; j < 8; ++j)
        lo[j] = (short)f2bf(vals[j] - bf2f((ushort)hi[j]));
      *(short8*)&buf[OW2 + rowA * 40 + kq] = lo;
    }
  };

  auto compute = [&](const ushort* buf) {
#pragma unroll
    for (int ks = 0; ks < 2; ++ks) {
      int ro = (w * 32 + l31) * 40 + ks * 16 + half * 8;
      short8 af = *(const short8*)&buf[OA + ro];
      short8 af2;
      if constexpr (MODE == 2) af2 = *(const short8*)&buf[OA2 + ro];
#pragma unroll
      for (int ct = 0; ct < 2; ++ct) {
        int co = (ct * 32 + l31) * 40 + ks * 16 + half * 8;
        short8 wf = *(const short8*)&buf[OW + co];
        if constexpr (MODE == 2) {
          short8 wf2 = *(const short8*)&buf[OW2 + co];
          acc[ct] = __builtin_amdgcn_mfma_f32_32x32x16_bf16(af, wf, acc[ct], 0, 0, 0);
          acc[ct] = __builtin_amdgcn_mfma_f32_32x32x16_bf16(af2, wf, acc[ct], 0, 0, 0);
          acc[ct] = __builtin_amdgcn_mfma_f32_32x32x16_bf16(af, wf2, acc[ct], 0, 0, 0);
        } else if (vmode) {
          acc[ct] = __builtin_amdgcn_mfma_f32_32x32x16_bf16(wf, af, acc[ct], 0, 0, 0);
        } else {
          acc[ct] = __builtin_amdgcn_mfma_f32_32x32x16_bf16(af, wf, acc[ct], 0, 0, 0);
        }
      }
    }
  };

  prefetch(0);
  store(bf0);
  __syncthreads();
  for (int i = 0; i < 8; ++i) {
    ushort* cur = (i & 1) ? bf1 : bf0;
    ushort* nxt = (i & 1) ? bf0 : bf1;
    if (i < 7) prefetch((i + 1) * 32);
    compute(cur);
    if (i < 7) store(nxt);
    __syncthreads();
  }

  // epilogue
#pragma unroll
  for (int ct = 0; ct < 2; ++ct) {
#pragma unroll
    for (int i = 0; i < 16; ++i) {
      int rl = (i & 3) + 8 * (i >> 2) + 4 * half;
      if constexpr (MODE == 0) {
        int r = r0 + w * 32 + rl;
        int c = c0 + ct * 32 + l31;
        int b = r >> 12, n = r & 4095;
        int h = c >> 5, d = c & 31;
        float v = (acc[ct][i] + bias[c]) * SLF;
        ((ushort*)out0)[((size_t)(b * 8 + h) * NN + n) * 32 + d] = f2bf(v);
      } else if constexpr (MODE == 1) {
        if (!vmode) {
          int r = r0 + w * 32 + rl;
          int c = c0 + ct * 32 + l31;
          int b = r >> 10, m = r & 1023;
          int h = c >> 5, d = c & 31;
          ((ushort*)out0)[((size_t)(b * 8 + h) * MM + m) * 32 + d] =
              f2bf(acc[ct][i] + bias[c]);
        } else {
          int c = c0 + ct * 32 + rl;        // swapped: rows of D are cols
          int r = r0 + w * 32 + l31;        // cols of D are A-rows (m)
          int b = r >> 10, m = r & 1023;
          int cv = c - 256;
          int h = cv >> 5, d = cv & 31;
          ((ushort*)out1)[((size_t)(b * 8 + h) * 32 + d) * MM + m] =
              f2bf(acc[ct][i] + bias[c]);
        }
      } else {
        int r = r0 + w * 32 + rl;
        int c = c0 + ct * 32 + l31;
        ((float*)out0)[(size_t)r * 256 + c] = acc[ct][i] + bias[c];
      }
    }
  }
}

// ---------------------------------------------------------------------------
// 4) MFMA flash attention (S^T = K·Q^T, O^T = V^T·P), exp2-domain softmax,
//    single-barrier double-buffered K/V staging. Output: hi/lo bf16 planes.
__global__ __launch_bounds__(256, 4) void attn_mfma(
    const ushort* __restrict__ qB, const ushort* __restrict__ kB,
    const ushort* __restrict__ vT, ushort* __restrict__ aH,
    ushort* __restrict__ aL) {
  __shared__ ushort sK[2][64][40];
  __shared__ ushort sVt[2][32][72];
  __shared__ ushort sP[128][72];
  int t = threadIdx.x;
  int lane = t & 63, w = t >> 6;
  int l31 = lane & 31, half = lane >> 5;
  int bh = blockIdx.x;
  int b = bh >> 3, h = bh & 7;
  int q0 = blockIdx.y * 128;

  const ushort* qrow = qB + ((size_t)bh * NN + q0 + w * 32 + l31) * 32;
  short8 bq0 = *(const short8*)(qrow + half * 8);
  short8 bq1 = *(const short8*)(qrow + 16 + half * 8);

  const ushort* kbase = kB + (size_t)bh * MM * 32;
  const ushort* vbase = vT + (size_t)bh * 32 * MM;
  int krow = t >> 2, kq = (t & 3) * 8;
  int vd = t >> 3, vmo = (t & 7) * 8;

  short8 kreg = *(const short8*)&kbase[(size_t)krow * 32 + kq];
  short8 vreg = *(const short8*)&vbase[(size_t)vd * MM + vmo];
  *(short8*)&sK[0][krow][kq] = kreg;
  *(short8*)&sVt[0][vd][vmo] = vreg;

  float m_run = -3.0e38f, l_run = 0.f;
  f32x16 o;
#pragma unroll
  for (int i = 0; i < 16; ++i) o[i] = 0.f;
  __syncthreads();

  for (int mc = 0; mc < 16; ++mc) {
    int cur = mc & 1, nxt = cur ^ 1;
    if (mc < 15) {
      int m0n = (mc + 1) * 64;
      kreg = *(const short8*)&kbase[(size_t)(m0n + krow) * 32 + kq];
      vreg = *(const short8*)&vbase[(size_t)vd * MM + m0n + vmo];
    }
    // S^T = K·Q^T : two 32x32 tiles
    f32x16 st[2];
#pragma unroll
    for (int tt = 0; tt < 2; ++tt) {
      short8 a0 = *(const short8*)&sK[cur][tt * 32 + l31][half * 8];
      short8 a1 = *(const short8*)&sK[cur][tt * 32 + l31][16 + half * 8];
      f32x16 z;
#pragma unroll
      for (int i = 0; i < 16; ++i) z[i] = 0.f;
      z = __builtin_amdgcn_mfma_f32_32x32x16_bf16(a0, bq0, z, 0, 0, 0);
      z = __builtin_amdgcn_mfma_f32_32x32x16_bf16(a1, bq1, z, 0, 0, 0);
      st[tt] = z;
    }

    // online softmax (log2 domain; scale pre-folded into q)
    float cm = st[0][0];
#pragma unroll
    for (int tt = 0; tt < 2; ++tt)
#pragma unroll
      for (int i = 0; i < 16; ++i) cm = fmaxf(cm, st[tt][i]);
    cm = fmaxf(cm, __shfl_xor(cm, 32));
    float nm = fmaxf(m_run, cm);
    float alpha = EXP2F(m_run - nm);
    float cs = 0.f;
#pragma unroll
    for (int tt = 0; tt < 2; ++tt) {
#pragma unroll
      for (int rg = 0; rg < 4; ++rg) {
        float p0 = EXP2F(st[tt][rg * 4 + 0] - nm);
        float p1 = EXP2F(st[tt][rg * 4 + 1] - nm);
        float p2 = EXP2F(st[tt][rg * 4 + 2] - nm);
        float p3 = EXP2F(st[tt][rg * 4 + 3] - nm);
        unsigned u0 = __builtin_bit_cast(unsigned, p0);
        unsigned u1 = __builtin_bit_cast(unsigned, p1);
        unsigned u2 = __builtin_bit_cast(unsigned, p2);
        unsigned u3 = __builtin_bit_cast(unsigned, p3);
        cs += __builtin_bit_cast(float, u0 & 0xffff0000u);
        cs += __builtin_bit_cast(float, u1 & 0xffff0000u);
        cs += __builtin_bit_cast(float, u2 & 0xffff0000u);
        cs += __builtin_bit_cast(float, u3 & 0xffff0000u);
        uint2 pk;
        pk.x = __builtin_amdgcn_perm(u1, u0, 0x07060302);
        pk.y = __builtin_amdgcn_perm(u3, u2, 0x07060302);
        *(uint2*)&sP[w * 32 + l31][tt * 32 + rg * 8 + half * 4] = pk;
      }
    }
    cs += __shfl_xor(cs, 32);
    l_run = l_run * alpha + cs;
    m_run = nm;
#pragma unroll
    for (int i = 0; i < 16; ++i) o[i] *= alpha;

    // O^T += V^T·P  (sP same-wave: no barrier needed)
#pragma unroll
    for (int kb = 0; kb < 4; ++kb) {
      short8 av = *(const short8*)&sVt[cur][l31][kb * 16 + half * 8];
      short8 bp = *(const short8*)&sP[w * 32 + l31][kb * 16 + half * 8];
      o = __builtin_amdgcn_mfma_f32_32x32x16_bf16(av, bp, o, 0, 0, 0);
    }

    if (mc < 15) {
      *(short8*)&sK[nxt][krow][kq] = kreg;
      *(short8*)&sVt[nxt][vd][vmo] = vreg;
    }
    __syncthreads();
  }

  // epilogue: hi/lo bf16 planes, row-major (B*N, 256)
  float inv = 1.f / l_run;
  size_t rbase = ((size_t)b * NN + q0 + w * 32 + l31) * 256 + h * 32;
#pragma unroll
  for (int rg = 0; rg < 4; ++rg) {
#pragma unroll
    for (int j = 0; j < 4; ++j) {
      float v = o[rg * 4 + j] * inv;
      ushort hi = f2bf(v);
      ushort lo = f2bf(v - bf2f(hi));
      int d = rg * 8 + half * 4 + j;
      aH[rbase + d] = hi;
      aL[rbase + d] = lo;
    }
  }
}

// ---------------------------------------------------------------------------
extern "C" void kernel_launch(void* const* d_in, const int* in_sizes, int n_in,
                              void* d_out, int out_size, void* d_ws, size_t ws_size,
                              hipStream_t stream) {
  const float* x      = (const float*)d_in[0];
  const float* dw_w   = (const float*)d_in[1];
  const float* dw_b   = (const float*)d_in[2];
  const float* pw_w   = (const float*)d_in[3];
  const float* pw_b   = (const float*)d_in[4];
  const float* sr_w   = (const float*)d_in[5];
  const float* ln_g   = (const float*)d_in[6];
  const float* ln_b   = (const float*)d_in[7];
  const float* kv_w   = (const float*)d_in[8];
  const float* kv_b   = (const float*)d_in[9];
  const float* proj_w = (const float*)d_in[10];
  const float* proj_b = (const float*)d_in[11];
  float* out = (float*)d_out;

  char* ws = (char*)d_ws;
  ushort* q1b = (ushort*)(ws);                  // 16384x256 bf16  (8 MB)
  ushort* xsr = (ushort*)(ws + (8u << 20));     // 4096x256        (2 MB)
  ushort* qB  = (ushort*)(ws + (16u << 20));    // 32x4096x32      (8 MB)
  ushort* kBp = (ushort*)(ws + (24u << 20));    // 32x1024x32      (2 MB)
  ushort* vTp = (ushort*)(ws + (26u << 20));    // 32x32x1024      (2 MB)
  ushort* aH  = (ushort*)(ws + (28u << 20));    // 16384x256       (8 MB)
  ushort* aL  = (ushort*)(ws + (36u << 20));    // 16384x256       (8 MB)

  const size_t smem_plain = 2 * (128 * 40 + 64 * 40) * sizeof(ushort);   // 30.7 KB
  const size_t smem_proj  = 2 * smem_plain;                              // 61.4 KB

  dwconv_kernel<<<dim3(128, BB), 256, 0, stream>>>(x, dw_w, dw_b, q1b);
  srln_kernel<<<dim3(MM, BB), 256, 0, stream>>>(x, sr_w, ln_g, ln_b, xsr);
  gemm_mfma<0><<<dim3(128, 4), 256, smem_plain, stream>>>(
      q1b, nullptr, pw_w, pw_b, qB, nullptr);
  gemm_mfma<1><<<dim3(32, 8), 256, smem_plain, stream>>>(
      xsr, nullptr, kv_w, kv_b, kBp, vTp);
  attn_mfma<<<dim3(32, 32), 256, 0, stream>>>(qB, kBp, vTp, aH, aL);
  gemm_mfma<2><<<dim3(128, 4), 256, smem_proj, stream>>>(
      aH, aL, proj_w, proj_b, out, nullptr);
}

// Round 5
// 171.720 us; speedup vs baseline: 3.7436x; 1.0487x over previous
//
#include <hip/hip_runtime.h>
#include <math.h>

#define BB 4
#define HH 64
#define WW 64
#define CC 256
#define NN 4096   // H*W
#define MM 1024   // (H/2)*(W/2)
#define LN_EPS 1e-6f
// ATTN_SCALE * log2(e), folded into q -> softmax uses exp2 directly
#define SLF (0.17677669529663687f * 1.4426950408889634f)

typedef __attribute__((ext_vector_type(8)))  short short8;
typedef __attribute__((ext_vector_type(16))) float f32x16;

__device__ __forceinline__ ushort f2bf(float f) {
  unsigned u = __builtin_bit_cast(unsigned, f);
  u += 0x7fffu + ((u >> 16) & 1u);   // RNE
  return (ushort)(u >> 16);
}
__device__ __forceinline__ float bf2f(ushort h) {
  unsigned u = ((unsigned)h) << 16;
  return __builtin_bit_cast(float, u);
}
#if __has_builtin(__builtin_amdgcn_exp2f)
#define EXP2F(x) __builtin_amdgcn_exp2f(x)
#else
#define EXP2F(x) exp2f(x)
#endif

// ---------------------------------------------------------------------------
// 1) FUSED front end: blocks [0,4096): srln (per output pos m, LayerNorm over C)
//                     blocks [4096,4608): dwconv row-streaming
__global__ __launch_bounds__(256) void pre_fused(
    const float* __restrict__ x, const float* __restrict__ dw_w,
    const float* __restrict__ dw_b, const float* __restrict__ sr_w,
    const float* __restrict__ ln_g, const float* __restrict__ ln_b,
    ushort* __restrict__ q1b, ushort* __restrict__ xsr) {
  int bid = blockIdx.x;
  int c = threadIdx.x;
  if (bid < 4096) {
    // ---- srln: depthwise 3x3 stride2 pad1 + LayerNorm -> bf16 ----
    int b = bid >> 10, m = bid & 1023;
    int my = m >> 5, mx = m & 31;
    const float* xb = x + (size_t)b * NN * CC + c;
    float acc = 0.f;
#pragma unroll
    for (int dy = 0; dy < 3; ++dy) {
      int iy = 2 * my + dy - 1;
      if (iy < 0 || iy >= HH) continue;
#pragma unroll
      for (int dx = 0; dx < 3; ++dx) {
        int ix = 2 * mx + dx - 1;
        if (ix < 0 || ix >= WW) continue;
        acc += xb[(size_t)(iy * WW + ix) * CC] * sr_w[c * 9 + dy * 3 + dx];
      }
    }
    float v1 = acc, v2 = acc * acc;
#pragma unroll
    for (int s = 1; s < 64; s <<= 1) {
      v1 += __shfl_xor(v1, s);
      v2 += __shfl_xor(v2, s);
    }
    __shared__ float r1[4], r2[4];
    int lane = c & 63, wv = c >> 6;
    if (lane == 0) { r1[wv] = v1; r2[wv] = v2; }
    __syncthreads();
    float s1 = r1[0] + r1[1] + r1[2] + r1[3];
    float s2 = r2[0] + r2[1] + r2[2] + r2[3];
    float mu = s1 * (1.f / 256.f);
    float var = s2 * (1.f / 256.f) - mu * mu;
    float yv = (acc - mu) * rsqrtf(var + LN_EPS) * ln_g[c] + ln_b[c];
    xsr[((size_t)b * MM + m) * CC + c] = f2bf(yv);
  } else {
    // ---- dwconv 3x3 stride1 pad1, row-streaming -> bf16 ----
    int id = bid - 4096;
    int b = id >> 7, yy = id & 127;
    int y = yy >> 1, hf = yy & 1;
    float wr[9];
#pragma unroll
    for (int i = 0; i < 9; ++i) wr[i] = dw_w[c * 9 + i];
    float bi = dw_b[c];
    const float* xb = x + (size_t)b * NN * CC + c;
    int x0 = hf * 32;
    bool okT = (y > 0), okB = (y < 63);
    float a0, a1, a2, b0, b1, b2;
    if (x0 == 0) {
      a0 = a1 = a2 = 0.f;
    } else {
      a0 = okT ? xb[(size_t)((y - 1) * 64 + x0 - 1) * CC] : 0.f;
      a1 = xb[(size_t)(y * 64 + x0 - 1) * CC];
      a2 = okB ? xb[(size_t)((y + 1) * 64 + x0 - 1) * CC] : 0.f;
    }
    b0 = okT ? xb[(size_t)((y - 1) * 64 + x0) * CC] : 0.f;
    b1 = xb[(size_t)(y * 64 + x0) * CC];
    b2 = okB ? xb[(size_t)((y + 1) * 64 + x0) * CC] : 0.f;
    ushort* ob = q1b + ((size_t)b * NN + y * 64) * CC + c;
#pragma unroll 8
    for (int xx = x0; xx < x0 + 32; ++xx) {
      float c0v, c1v, c2v;
      if (xx < 63) {
        c0v = okT ? xb[(size_t)((y - 1) * 64 + xx + 1) * CC] : 0.f;
        c1v = xb[(size_t)(y * 64 + xx + 1) * CC];
        c2v = okB ? xb[(size_t)((y + 1) * 64 + xx + 1) * CC] : 0.f;
      } else {
        c0v = c1v = c2v = 0.f;
      }
      float acc = bi;
      acc += a0 * wr[0] + b0 * wr[1] + c0v * wr[2];
      acc += a1 * wr[3] + b1 * wr[4] + c1v * wr[5];
      acc += a2 * wr[6] + b2 * wr[7] + c2v * wr[8];
      ob[(size_t)xx * CC] = f2bf(acc);
      a0 = b0; a1 = b1; a2 = b2;
      b0 = c0v; b1 = c1v; b2 = c2v;
    }
  }
}

// ---------------------------------------------------------------------------
// 2) FUSED q-GEMM + kv-GEMM. 64x64 tiles, 4 waves (32x32 quadrants),
//    double-buffered single-barrier. blocks [0,1024): q pw-GEMM -> qB (*SLF).
//    blocks [1024,1536): kv-GEMM -> kB (c<256) / vT transposed (c>=256).
__global__ __launch_bounds__(256) void gemm_qkv(
    const ushort* __restrict__ q1b, const ushort* __restrict__ xsr,
    const float* __restrict__ pw_w, const float* __restrict__ pw_b,
    const float* __restrict__ kv_w, const float* __restrict__ kv_b,
    ushort* __restrict__ qB, ushort* __restrict__ kB,
    ushort* __restrict__ vT) {
  __shared__ ushort smem[2][128 * 40];   // A at 0, W at 64*40
  int bid = blockIdx.x;
  bool is0 = bid < 1024;
  const ushort* A;
  const float* W;
  const float* bias;
  int r0, c0;
  if (is0) {
    A = q1b; W = pw_w; bias = pw_b;
    r0 = (bid >> 2) * 64; c0 = (bid & 3) * 64;
  } else {
    int sid = bid - 1024;
    A = xsr; W = kv_w; bias = kv_b;
    r0 = (sid >> 3) * 64; c0 = (sid & 7) * 64;
  }
  const bool vmode = (!is0) && (c0 >= 256);

  int t = threadIdx.x;
  int lane = t & 63, w = t >> 6;
  int l31 = lane & 31, half = lane >> 5;
  int wr = w >> 1, wc = w & 1;
  int rowA = t >> 2, kq = (t & 3) * 8;

  f32x16 acc;
#pragma unroll
  for (int i = 0; i < 16; ++i) acc[i] = 0.f;

  short8 ra;
  float4 rw0, rw1;
  auto prefetch = [&](int kc) {
    ra = *(const short8*)&A[(size_t)(r0 + rowA) * 256 + kc + kq];
    const float* wp = &W[(size_t)(c0 + rowA) * 256 + kc + kq];
    rw0 = *(const float4*)wp;
    rw1 = *(const float4*)(wp + 4);
  };
  auto store = [&](ushort* buf) {
    *(short8*)&buf[rowA * 40 + kq] = ra;
    float vals[8] = {rw0.x, rw0.y, rw0.z, rw0.w, rw1.x, rw1.y, rw1.z, rw1.w};
    short8 hi;
#pragma unroll
    for (int j = 0; j < 8; ++j) hi[j] = (short)f2bf(vals[j]);
    *(short8*)&buf[64 * 40 + rowA * 40 + kq] = hi;
  };
  auto compute = [&](const ushort* buf) {
#pragma unroll
    for (int ks = 0; ks < 2; ++ks) {
      short8 af = *(const short8*)&buf[(wr * 32 + l31) * 40 + ks * 16 + half * 8];
      short8 wf = *(const short8*)&buf[64 * 40 + (wc * 32 + l31) * 40 + ks * 16 + half * 8];
      if (vmode)
        acc = __builtin_amdgcn_mfma_f32_32x32x16_bf16(wf, af, acc, 0, 0, 0);
      else
        acc = __builtin_amdgcn_mfma_f32_32x32x16_bf16(af, wf, acc, 0, 0, 0);
    }
  };

  prefetch(0);
  store(smem[0]);
  __syncthreads();
  for (int i = 0; i < 8; ++i) {
    ushort* cur = smem[i & 1];
    ushort* nxt = smem[(i & 1) ^ 1];
    if (i < 7) prefetch((i + 1) * 32);
    compute(cur);
    if (i < 7) store(nxt);
    __syncthreads();
  }

#pragma unroll
  for (int i = 0; i < 16; ++i) {
    int rl = (i & 3) + 8 * (i >> 2) + 4 * half;
    if (is0) {
      int r = r0 + wr * 32 + rl;
      int c = c0 + wc * 32 + l31;
      int b = r >> 12, n = r & 4095;
      int h = c >> 5, d = c & 31;
      qB[((size_t)(b * 8 + h) * NN + n) * 32 + d] =
          f2bf((acc[i] + bias[c]) * SLF);
    } else if (!vmode) {
      int r = r0 + wr * 32 + rl;
      int c = c0 + wc * 32 + l31;
      int b = r >> 10, m = r & 1023;
      int h = c >> 5, d = c & 31;
      kB[((size_t)(b * 8 + h) * MM + m) * 32 + d] = f2bf(acc[i] + bias[c]);
    } else {
      int c = c0 + wc * 32 + rl;        // swapped: D rows = W cols
      int r = r0 + wr * 32 + l31;       // D cols = A rows (m)
      int b = r >> 10, m = r & 1023;
      int cv = c - 256;
      int h = cv >> 5, d = cv & 31;
      vT[((size_t)(b * 8 + h) * 32 + d) * MM + m] = f2bf(acc[i] + bias[c]);
    }
  }
}

// ---------------------------------------------------------------------------
// 3) MFMA flash attention (S^T = K·Q^T, O^T = V^T·P), exp2-domain softmax,
//    single-barrier double-buffered K/V staging. Output: hi/lo bf16 planes.
__global__ __launch_bounds__(256, 4) void attn_mfma(
    const ushort* __restrict__ qB, const ushort* __restrict__ kB,
    const ushort* __restrict__ vT, ushort* __restrict__ aH,
    ushort* __restrict__ aL) {
  __shared__ ushort sK[2][64][40];
  __shared__ ushort sVt[2][32][72];
  __shared__ ushort sP[128][72];
  int t = threadIdx.x;
  int lane = t & 63, w = t >> 6;
  int l31 = lane & 31, half = lane >> 5;
  int bh = blockIdx.x;
  int b = bh >> 3, h = bh & 7;
  int q0 = blockIdx.y * 128;

  const ushort* qrow = qB + ((size_t)bh * NN + q0 + w * 32 + l31) * 32;
  short8 bq0 = *(const short8*)(qrow + half * 8);
  short8 bq1 = *(const short8*)(qrow + 16 + half * 8);

  const ushort* kbase = kB + (size_t)bh * MM * 32;
  const ushort* vbase = vT + (size_t)bh * 32 * MM;
  int krow = t >> 2, kq = (t & 3) * 8;
  int vd = t >> 3, vmo = (t & 7) * 8;

  short8 kreg = *(const short8*)&kbase[(size_t)krow * 32 + kq];
  short8 vreg = *(const short8*)&vbase[(size_t)vd * MM + vmo];
  *(short8*)&sK[0][krow][kq] = kreg;
  *(short8*)&sVt[0][vd][vmo] = vreg;

  float m_run = -3.0e38f, l_run = 0.f;
  f32x16 o;
#pragma unroll
  for (int i = 0; i < 16; ++i) o[i] = 0.f;
  __syncthreads();

  for (int mc = 0; mc < 16; ++mc) {
    int cur = mc & 1, nxt = cur ^ 1;
    if (mc < 15) {
      int m0n = (mc + 1) * 64;
      kreg = *(const short8*)&kbase[(size_t)(m0n + krow) * 32 + kq];
      vreg = *(const short8*)&vbase[(size_t)vd * MM + m0n + vmo];
    }
    f32x16 st[2];
#pragma unroll
    for (int tt = 0; tt < 2; ++tt) {
      short8 a0 = *(const short8*)&sK[cur][tt * 32 + l31][half * 8];
      short8 a1 = *(const short8*)&sK[cur][tt * 32 + l31][16 + half * 8];
      f32x16 z;
#pragma unroll
      for (int i = 0; i < 16; ++i) z[i] = 0.f;
      z = __builtin_amdgcn_mfma_f32_32x32x16_bf16(a0, bq0, z, 0, 0, 0);
      z = __builtin_amdgcn_mfma_f32_32x32x16_bf16(a1, bq1, z, 0, 0, 0);
      st[tt] = z;
    }

    float cm = st[0][0];
#pragma unroll
    for (int tt = 0; tt < 2; ++tt)
#pragma unroll
      for (int i = 0; i < 16; ++i) cm = fmaxf(cm, st[tt][i]);
    cm = fmaxf(cm, __shfl_xor(cm, 32));
    float nm = fmaxf(m_run, cm);
    float alpha = EXP2F(m_run - nm);
    float cs = 0.f;
#pragma unroll
    for (int tt = 0; tt < 2; ++tt) {
#pragma unroll
      for (int rg = 0; rg < 4; ++rg) {
        float p0 = EXP2F(st[tt][rg * 4 + 0] - nm);
        float p1 = EXP2F(st[tt][rg * 4 + 1] - nm);
        float p2 = EXP2F(st[tt][rg * 4 + 2] - nm);
        float p3 = EXP2F(st[tt][rg * 4 + 3] - nm);
        unsigned u0 = __builtin_bit_cast(unsigned, p0);
        unsigned u1 = __builtin_bit_cast(unsigned, p1);
        unsigned u2 = __builtin_bit_cast(unsigned, p2);
        unsigned u3 = __builtin_bit_cast(unsigned, p3);
        cs += __builtin_bit_cast(float, u0 & 0xffff0000u);
        cs += __builtin_bit_cast(float, u1 & 0xffff0000u);
        cs += __builtin_bit_cast(float, u2 & 0xffff0000u);
        cs += __builtin_bit_cast(float, u3 & 0xffff0000u);
        uint2 pk;
        pk.x = __builtin_amdgcn_perm(u1, u0, 0x07060302);
        pk.y = __builtin_amdgcn_perm(u3, u2, 0x07060302);
        *(uint2*)&sP[w * 32 + l31][tt * 32 + rg * 8 + half * 4] = pk;
      }
    }
    cs += __shfl_xor(cs, 32);
    l_run = l_run * alpha + cs;
    m_run = nm;
#pragma unroll
    for (int i = 0; i < 16; ++i) o[i] *= alpha;

#pragma unroll
    for (int kb = 0; kb < 4; ++kb) {
      short8 av = *(const short8*)&sVt[cur][l31][kb * 16 + half * 8];
      short8 bp = *(const short8*)&sP[w * 32 + l31][kb * 16 + half * 8];
      o = __builtin_amdgcn_mfma_f32_32x32x16_bf16(av, bp, o, 0, 0, 0);
    }

    if (mc < 15) {
      *(short8*)&sK[nxt][krow][kq] = kreg;
      *(short8*)&sVt[nxt][vd][vmo] = vreg;
    }
    __syncthreads();
  }

  float inv = 1.f / l_run;
  size_t rbase = ((size_t)b * NN + q0 + w * 32 + l31) * 256 + h * 32;
#pragma unroll
  for (int rg = 0; rg < 4; ++rg) {
#pragma unroll
    for (int j = 0; j < 4; ++j) {
      float v = o[rg * 4 + j] * inv;
      ushort hi = f2bf(v);
      ushort lo = f2bf(v - bf2f(hi));
      int d = rg * 8 + half * 4 + j;
      aH[rbase + d] = hi;
      aL[rbase + d] = lo;
    }
  }
}

// ---------------------------------------------------------------------------
// 4) proj GEMM, hi/lo split on A and W, 64x64 tiles, single-buffer LDS
//    (20.5 KB -> grid-limited 4 blocks/CU), register prefetch, 2 barriers.
__global__ __launch_bounds__(256) void gemm_proj(
    const ushort* __restrict__ A, const ushort* __restrict__ A2,
    const float* __restrict__ W, const float* __restrict__ bias,
    float* __restrict__ out) {
  __shared__ ushort smem[4 * 64 * 40];   // A | A2 | Whi | Wlo
  constexpr int OA = 0, OA2 = 64 * 40, OW = 2 * 64 * 40, OW2 = 3 * 64 * 40;
  int bid = blockIdx.x;
  int r0 = (bid >> 2) * 64, c0 = (bid & 3) * 64;

  int t = threadIdx.x;
  int lane = t & 63, w = t >> 6;
  int l31 = lane & 31, half = lane >> 5;
  int wr = w >> 1, wc = w & 1;
  int rowA = t >> 2, kq = (t & 3) * 8;

  f32x16 acc;
#pragma unroll
  for (int i = 0; i < 16; ++i) acc[i] = 0.f;

  short8 ra, ra2;
  float4 rw0, rw1;
  auto prefetch = [&](int kc) {
    ra = *(const short8*)&A[(size_t)(r0 + rowA) * 256 + kc + kq];
    ra2 = *(const short8*)&A2[(size_t)(r0 + rowA) * 256 + kc + kq];
    const float* wp = &W[(size_t)(c0 + rowA) * 256 + kc + kq];
    rw0 = *(const float4*)wp;
    rw1 = *(const float4*)(wp + 4);
  };
  auto store = [&]() {
    *(short8*)&smem[OA + rowA * 40 + kq] = ra;
    *(short8*)&smem[OA2 + rowA * 40 + kq] = ra2;
    float vals[8] = {rw0.x, rw0.y, rw0.z, rw0.w, rw1.x, rw1.y, rw1.z, rw1.w};
    short8 hi, lo;
#pragma unroll
    for (int j = 0; j < 8; ++j) {
      hi[j] = (short)f2bf(vals[j]);
      lo[j] = (short)f2bf(vals[j] - bf2f((ushort)hi[j]));
    }
    *(short8*)&smem[OW + rowA * 40 + kq] = hi;
    *(short8*)&smem[OW2 + rowA * 40 + kq] = lo;
  };

  prefetch(0);
  store();
  __syncthreads();
  for (int i = 0; i < 8; ++i) {
    if (i < 7) prefetch((i + 1) * 32);
#pragma unroll
    for (int ks = 0; ks < 2; ++ks) {
      int ro = (wr * 32 + l31) * 40 + ks * 16 + half * 8;
      int co = (wc * 32 + l31) * 40 + ks * 16 + half * 8;
      short8 af = *(const short8*)&smem[OA + ro];
      short8 af2 = *(const short8*)&smem[OA2 + ro];
      short8 wf = *(const short8*)&smem[OW + co];
      short8 wf2 = *(const short8*)&smem[OW2 + co];
      acc = __builtin_amdgcn_mfma_f32_32x32x16_bf16(af, wf, acc, 0, 0, 0);
      acc = __builtin_amdgcn_mfma_f32_32x32x16_bf16(af2, wf, acc, 0, 0, 0);
      acc = __builtin_amdgcn_mfma_f32_32x32x16_bf16(af, wf2, acc, 0, 0, 0);
    }
    __syncthreads();
    if (i < 7) {
      store();
      __syncthreads();
    }
  }

#pragma unroll
  for (int i = 0; i < 16; ++i) {
    int rl = (i & 3) + 8 * (i >> 2) + 4 * half;
    int r = r0 + wr * 32 + rl;
    int c = c0 + wc * 32 + l31;
    out[(size_t)r * 256 + c] = acc[i] + bias[c];
  }
}

// ---------------------------------------------------------------------------
extern "C" void kernel_launch(void* const* d_in, const int* in_sizes, int n_in,
                              void* d_out, int out_size, void* d_ws, size_t ws_size,
                              hipStream_t stream) {
  const float* x      = (const float*)d_in[0];
  const float* dw_w   = (const float*)d_in[1];
  const float* dw_b   = (const float*)d_in[2];
  const float* pw_w   = (const float*)d_in[3];
  const float* pw_b   = (const float*)d_in[4];
  const float* sr_w   = (const float*)d_in[5];
  const float* ln_g   = (const float*)d_in[6];
  const float* ln_b   = (const float*)d_in[7];
  const float* kv_w   = (const float*)d_in[8];
  const float* kv_b   = (const float*)d_in[9];
  const float* proj_w = (const float*)d_in[10];
  const float* proj_b = (const float*)d_in[11];
  float* out = (float*)d_out;

  char* ws = (char*)d_ws;
  ushort* q1b = (ushort*)(ws);                  // 16384x256 bf16  (8 MB)
  ushort* xsr = (ushort*)(ws + (8u << 20));     // 4096x256        (2 MB)
  ushort* qB  = (ushort*)(ws + (16u << 20));    // 32x4096x32      (8 MB)
  ushort* kBp = (ushort*)(ws + (24u << 20));    // 32x1024x32      (2 MB)
  ushort* vTp = (ushort*)(ws + (26u << 20));    // 32x32x1024      (2 MB)
  ushort* aH  = (ushort*)(ws + (28u << 20));    // 16384x256       (8 MB)
  ushort* aL  = (ushort*)(ws + (36u << 20));    // 16384x256       (8 MB)

  pre_fused<<<dim3(4608), 256, 0, stream>>>(x, dw_w, dw_b, sr_w, ln_g, ln_b,
                                            q1b, xsr);
  gemm_qkv<<<dim3(1536), 256, 0, stream>>>(q1b, xsr, pw_w, pw_b, kv_w, kv_b,
                                           qB, kBp, vTp);
  attn_mfma<<<dim3(32, 32), 256, 0, stream>>>(qB, kBp, vTp, aH, aL);
  gemm_proj<<<dim3(1024), 256, 0, stream>>>(aH, aL, proj_w, proj_b, out);
}

// Round 6
// 171.222 us; speedup vs baseline: 3.7545x; 1.0029x over previous
//
#include <hip/hip_runtime.h>
#include <math.h>

#define BB 4
#define HH 64
#define WW 64
#define CC 256
#define NN 4096   // H*W
#define MM 1024   // (H/2)*(W/2)
#define LN_EPS 1e-6f
// ATTN_SCALE * log2(e), folded into q -> softmax uses exp2 directly
#define SLF (0.17677669529663687f * 1.4426950408889634f)

typedef __attribute__((ext_vector_type(8)))  short short8;
typedef __attribute__((ext_vector_type(16))) float f32x16;

__device__ __forceinline__ ushort f2bf(float f) {
  unsigned u = __builtin_bit_cast(unsigned, f);
  u += 0x7fffu + ((u >> 16) & 1u);   // RNE
  return (ushort)(u >> 16);
}
__device__ __forceinline__ float bf2f(ushort h) {
  unsigned u = ((unsigned)h) << 16;
  return __builtin_bit_cast(float, u);
}
#if __has_builtin(__builtin_amdgcn_exp2f)
#define EXP2F(x) __builtin_amdgcn_exp2f(x)
#else
#define EXP2F(x) exp2f(x)
#endif

// ---------------------------------------------------------------------------
// 1) FUSED front end: blocks [0,4096): srln; blocks [4096,4608): dwconv
__global__ __launch_bounds__(256) void pre_fused(
    const float* __restrict__ x, const float* __restrict__ dw_w,
    const float* __restrict__ dw_b, const float* __restrict__ sr_w,
    const float* __restrict__ ln_g, const float* __restrict__ ln_b,
    ushort* __restrict__ q1b, ushort* __restrict__ xsr) {
  int bid = blockIdx.x;
  int c = threadIdx.x;
  if (bid < 4096) {
    int b = bid >> 10, m = bid & 1023;
    int my = m >> 5, mx = m & 31;
    const float* xb = x + (size_t)b * NN * CC + c;
    float acc = 0.f;
#pragma unroll
    for (int dy = 0; dy < 3; ++dy) {
      int iy = 2 * my + dy - 1;
      if (iy < 0 || iy >= HH) continue;
#pragma unroll
      for (int dx = 0; dx < 3; ++dx) {
        int ix = 2 * mx + dx - 1;
        if (ix < 0 || ix >= WW) continue;
        acc += xb[(size_t)(iy * WW + ix) * CC] * sr_w[c * 9 + dy * 3 + dx];
      }
    }
    float v1 = acc, v2 = acc * acc;
#pragma unroll
    for (int s = 1; s < 64; s <<= 1) {
      v1 += __shfl_xor(v1, s);
      v2 += __shfl_xor(v2, s);
    }
    __shared__ float r1[4], r2[4];
    int lane = c & 63, wv = c >> 6;
    if (lane == 0) { r1[wv] = v1; r2[wv] = v2; }
    __syncthreads();
    float s1 = r1[0] + r1[1] + r1[2] + r1[3];
    float s2 = r2[0] + r2[1] + r2[2] + r2[3];
    float mu = s1 * (1.f / 256.f);
    float var = s2 * (1.f / 256.f) - mu * mu;
    float yv = (acc - mu) * rsqrtf(var + LN_EPS) * ln_g[c] + ln_b[c];
    xsr[((size_t)b * MM + m) * CC + c] = f2bf(yv);
  } else {
    int id = bid - 4096;
    int b = id >> 7, yy = id & 127;
    int y = yy >> 1, hf = yy & 1;
    float wr[9];
#pragma unroll
    for (int i = 0; i < 9; ++i) wr[i] = dw_w[c * 9 + i];
    float bi = dw_b[c];
    const float* xb = x + (size_t)b * NN * CC + c;
    int x0 = hf * 32;
    bool okT = (y > 0), okB = (y < 63);
    float a0, a1, a2, b0, b1, b2;
    if (x0 == 0) {
      a0 = a1 = a2 = 0.f;
    } else {
      a0 = okT ? xb[(size_t)((y - 1) * 64 + x0 - 1) * CC] : 0.f;
      a1 = xb[(size_t)(y * 64 + x0 - 1) * CC];
      a2 = okB ? xb[(size_t)((y + 1) * 64 + x0 - 1) * CC] : 0.f;
    }
    b0 = okT ? xb[(size_t)((y - 1) * 64 + x0) * CC] : 0.f;
    b1 = xb[(size_t)(y * 64 + x0) * CC];
    b2 = okB ? xb[(size_t)((y + 1) * 64 + x0) * CC] : 0.f;
    ushort* ob = q1b + ((size_t)b * NN + y * 64) * CC + c;
#pragma unroll 8
    for (int xx = x0; xx < x0 + 32; ++xx) {
      float c0v, c1v, c2v;
      if (xx < 63) {
        c0v = okT ? xb[(size_t)((y - 1) * 64 + xx + 1) * CC] : 0.f;
        c1v = xb[(size_t)(y * 64 + xx + 1) * CC];
        c2v = okB ? xb[(size_t)((y + 1) * 64 + xx + 1) * CC] : 0.f;
      } else {
        c0v = c1v = c2v = 0.f;
      }
      float acc = bi;
      acc += a0 * wr[0] + b0 * wr[1] + c0v * wr[2];
      acc += a1 * wr[3] + b1 * wr[4] + c1v * wr[5];
      acc += a2 * wr[6] + b2 * wr[7] + c2v * wr[8];
      ob[(size_t)xx * CC] = f2bf(acc);
      a0 = b0; a1 = b1; a2 = b2;
      b0 = c0v; b1 = c1v; b2 = c2v;
    }
  }
}

// ---------------------------------------------------------------------------
// 2) FUSED q-GEMM + kv-GEMM. 64x64 tiles, double-buffered single-barrier.
__global__ __launch_bounds__(256) void gemm_qkv(
    const ushort* __restrict__ q1b, const ushort* __restrict__ xsr,
    const float* __restrict__ pw_w, const float* __restrict__ pw_b,
    const float* __restrict__ kv_w, const float* __restrict__ kv_b,
    ushort* __restrict__ qB, ushort* __restrict__ kB,
    ushort* __restrict__ vT) {
  __shared__ ushort smem[2][128 * 40];
  int bid = blockIdx.x;
  bool is0 = bid < 1024;
  const ushort* A;
  const float* W;
  const float* bias;
  int r0, c0;
  if (is0) {
    A = q1b; W = pw_w; bias = pw_b;
    r0 = (bid >> 2) * 64; c0 = (bid & 3) * 64;
  } else {
    int sid = bid - 1024;
    A = xsr; W = kv_w; bias = kv_b;
    r0 = (sid >> 3) * 64; c0 = (sid & 7) * 64;
  }
  const bool vmode = (!is0) && (c0 >= 256);

  int t = threadIdx.x;
  int lane = t & 63, w = t >> 6;
  int l31 = lane & 31, half = lane >> 5;
  int wr = w >> 1, wc = w & 1;
  int rowA = t >> 2, kq = (t & 3) * 8;

  f32x16 acc;
#pragma unroll
  for (int i = 0; i < 16; ++i) acc[i] = 0.f;

  short8 ra;
  float4 rw0, rw1;
  auto prefetch = [&](int kc) {
    ra = *(const short8*)&A[(size_t)(r0 + rowA) * 256 + kc + kq];
    const float* wp = &W[(size_t)(c0 + rowA) * 256 + kc + kq];
    rw0 = *(const float4*)wp;
    rw1 = *(const float4*)(wp + 4);
  };
  auto store = [&](ushort* buf) {
    *(short8*)&buf[rowA * 40 + kq] = ra;
    float vals[8] = {rw0.x, rw0.y, rw0.z, rw0.w, rw1.x, rw1.y, rw1.z, rw1.w};
    short8 hi;
#pragma unroll
    for (int j = 0; j < 8; ++j) hi[j] = (short)f2bf(vals[j]);
    *(short8*)&buf[64 * 40 + rowA * 40 + kq] = hi;
  };
  auto compute = [&](const ushort* buf) {
#pragma unroll
    for (int ks = 0; ks < 2; ++ks) {
      short8 af = *(const short8*)&buf[(wr * 32 + l31) * 40 + ks * 16 + half * 8];
      short8 wf = *(const short8*)&buf[64 * 40 + (wc * 32 + l31) * 40 + ks * 16 + half * 8];
      if (vmode)
        acc = __builtin_amdgcn_mfma_f32_32x32x16_bf16(wf, af, acc, 0, 0, 0);
      else
        acc = __builtin_amdgcn_mfma_f32_32x32x16_bf16(af, wf, acc, 0, 0, 0);
    }
  };

  prefetch(0);
  store(smem[0]);
  __syncthreads();
  for (int i = 0; i < 8; ++i) {
    ushort* cur = smem[i & 1];
    ushort* nxt = smem[(i & 1) ^ 1];
    if (i < 7) prefetch((i + 1) * 32);
    compute(cur);
    if (i < 7) store(nxt);
    __syncthreads();
  }

#pragma unroll
  for (int i = 0; i < 16; ++i) {
    int rl = (i & 3) + 8 * (i >> 2) + 4 * half;
    if (is0) {
      int r = r0 + wr * 32 + rl;
      int c = c0 + wc * 32 + l31;
      int b = r >> 12, n = r & 4095;
      int h = c >> 5, d = c & 31;
      qB[((size_t)(b * 8 + h) * NN + n) * 32 + d] =
          f2bf((acc[i] + bias[c]) * SLF);
    } else if (!vmode) {
      int r = r0 + wr * 32 + rl;
      int c = c0 + wc * 32 + l31;
      int b = r >> 10, m = r & 1023;
      int h = c >> 5, d = c & 31;
      kB[((size_t)(b * 8 + h) * MM + m) * 32 + d] = f2bf(acc[i] + bias[c]);
    } else {
      int c = c0 + wc * 32 + rl;
      int r = r0 + wr * 32 + l31;
      int b = r >> 10, m = r & 1023;
      int cv = c - 256;
      int h = cv >> 5, d = cv & 31;
      vT[((size_t)(b * 8 + h) * 32 + d) * MM + m] = f2bf(acc[i] + bias[c]);
    }
  }
}

// ---------------------------------------------------------------------------
// 3) MFMA flash attention — fragment-major LDS layouts, conflict-free.
//    sKa regions: [buf][tt*4 + ks*2 + half][33 lanes x 8 shorts]
//    sVa regions: [buf][kb*2 + half][33 lanes x 8 shorts]
//    pB (P in B-frag layout, per-wave): [w][kb][64 lanes x 8 shorts]
__global__ __launch_bounds__(256, 4) void attn_mfma(
    const ushort* __restrict__ qB, const ushort* __restrict__ kB,
    const ushort* __restrict__ vT, ushort* __restrict__ aH,
    ushort* __restrict__ aL) {
  __shared__ ushort sKa[2][8][264];   // 8448 B
  __shared__ ushort sVa[2][8][264];   // 8448 B
  __shared__ ushort pB[4][4][512];    // 16384 B
  int t = threadIdx.x;
  int lane = t & 63, w = t >> 6;
  int l31 = lane & 31, half = lane >> 5;
  int bh = blockIdx.x;
  int b = bh >> 3, h = bh & 7;
  int q0 = blockIdx.y * 128;

  const ushort* qrow = qB + ((size_t)bh * NN + q0 + w * 32 + l31) * 32;
  short8 bq0 = *(const short8*)(qrow + half * 8);
  short8 bq1 = *(const short8*)(qrow + 16 + half * 8);

  const ushort* kbase = kB + (size_t)bh * MM * 32;
  const ushort* vbase = vT + (size_t)bh * 32 * MM;
  int krow = t >> 2, kq = (t & 3) * 8;          // K: row m, d-offset
  int vd = t >> 3, vmo = (t & 7) * 8;           // V: row d, m-offset
  // frag-major region indices for staging
  int kreg_idx = (krow >> 5) * 4 + (kq >> 4) * 2 + ((kq >> 3) & 1);
  int klane = (krow & 31) * 8;
  int vreg_idx = (vmo >> 4) * 2 + ((vmo >> 3) & 1);
  int vlane = vd * 8;

  short8 kreg = *(const short8*)&kbase[(size_t)krow * 32 + kq];
  short8 vreg = *(const short8*)&vbase[(size_t)vd * MM + vmo];
  *(short8*)&sKa[0][kreg_idx][klane] = kreg;
  *(short8*)&sVa[0][vreg_idx][vlane] = vreg;

  float m_run = -3.0e38f, l_run = 0.f;
  f32x16 o;
#pragma unroll
  for (int i = 0; i < 16; ++i) o[i] = 0.f;
  __syncthreads();

  for (int mc = 0; mc < 16; ++mc) {
    int cur = mc & 1, nxt = cur ^ 1;
    if (mc < 15) {
      int m0n = (mc + 1) * 64;
      kreg = *(const short8*)&kbase[(size_t)(m0n + krow) * 32 + kq];
      vreg = *(const short8*)&vbase[(size_t)vd * MM + m0n + vmo];
    }
    // S^T = K·Q^T : two 32x32 tiles (A-frags from frag-major sKa)
    f32x16 st[2];
#pragma unroll
    for (int tt = 0; tt < 2; ++tt) {
      short8 a0 = *(const short8*)&sKa[cur][tt * 4 + 0 + half][l31 * 8];
      short8 a1 = *(const short8*)&sKa[cur][tt * 4 + 2 + half][l31 * 8];
      f32x16 z;
#pragma unroll
      for (int i = 0; i < 16; ++i) z[i] = 0.f;
      z = __builtin_amdgcn_mfma_f32_32x32x16_bf16(a0, bq0, z, 0, 0, 0);
      z = __builtin_amdgcn_mfma_f32_32x32x16_bf16(a1, bq1, z, 0, 0, 0);
      st[tt] = z;
    }

    // online softmax (log2 domain)
    float cm = st[0][0];
#pragma unroll
    for (int tt = 0; tt < 2; ++tt)
#pragma unroll
      for (int i = 0; i < 16; ++i) cm = fmaxf(cm, st[tt][i]);
    cm = fmaxf(cm, __shfl_xor(cm, 32));
    float nm = fmaxf(m_run, cm);
    float alpha = EXP2F(m_run - nm);
    float cs = 0.f;
#pragma unroll
    for (int tt = 0; tt < 2; ++tt) {
#pragma unroll
      for (int rg = 0; rg < 4; ++rg) {
        float p0 = EXP2F(st[tt][rg * 4 + 0] - nm);
        float p1 = EXP2F(st[tt][rg * 4 + 1] - nm);
        float p2 = EXP2F(st[tt][rg * 4 + 2] - nm);
        float p3 = EXP2F(st[tt][rg * 4 + 3] - nm);
        unsigned u0 = __builtin_bit_cast(unsigned, p0);
        unsigned u1 = __builtin_bit_cast(unsigned, p1);
        unsigned u2 = __builtin_bit_cast(unsigned, p2);
        unsigned u3 = __builtin_bit_cast(unsigned, p3);
        cs += __builtin_bit_cast(float, u0 & 0xffff0000u);
        cs += __builtin_bit_cast(float, u1 & 0xffff0000u);
        cs += __builtin_bit_cast(float, u2 & 0xffff0000u);
        cs += __builtin_bit_cast(float, u3 & 0xffff0000u);
        uint2 pk;
        pk.x = __builtin_amdgcn_perm(u1, u0, 0x07060302);
        pk.y = __builtin_amdgcn_perm(u3, u2, 0x07060302);
        // frag-major P: m = 32*tt + 8*rg + 4*half + j'
        //   kb = 2*tt + (rg>>1); dest lane = (rg&1)*32 + l31; k-off = 4*half
        *(uint2*)&pB[w][2 * tt + (rg >> 1)][((rg & 1) * 32 + l31) * 8 + 4 * half] = pk;
      }
    }
    cs += __shfl_xor(cs, 32);
    l_run = l_run * alpha + cs;
    m_run = nm;
#pragma unroll
    for (int i = 0; i < 16; ++i) o[i] *= alpha;

    // O^T += V^T·P  (pB same-wave: no barrier; frag-major b128 reads)
#pragma unroll
    for (int kb = 0; kb < 4; ++kb) {
      short8 av = *(const short8*)&sVa[cur][kb * 2 + half][l31 * 8];
      short8 bp = *(const short8*)&pB[w][kb][lane * 8];
      o = __builtin_amdgcn_mfma_f32_32x32x16_bf16(av, bp, o, 0, 0, 0);
    }

    if (mc < 15) {
      *(short8*)&sKa[nxt][kreg_idx][klane] = kreg;
      *(short8*)&sVa[nxt][vreg_idx][vlane] = vreg;
    }
    __syncthreads();
  }

  float inv = 1.f / l_run;
  size_t rbase = ((size_t)b * NN + q0 + w * 32 + l31) * 256 + h * 32;
#pragma unroll
  for (int rg = 0; rg < 4; ++rg) {
#pragma unroll
    for (int j = 0; j < 4; ++j) {
      float v = o[rg * 4 + j] * inv;
      ushort hi = f2bf(v);
      ushort lo = f2bf(v - bf2f(hi));
      int d = rg * 8 + half * 4 + j;
      aH[rbase + d] = hi;
      aL[rbase + d] = lo;
    }
  }
}

// ---------------------------------------------------------------------------
// 4) proj GEMM, hi/lo split on A and W, 64x64 tiles, single-buffer LDS.
__global__ __launch_bounds__(256) void gemm_proj(
    const ushort* __restrict__ A, const ushort* __restrict__ A2,
    const float* __restrict__ W, const float* __restrict__ bias,
    float* __restrict__ out) {
  __shared__ ushort smem[4 * 64 * 40];
  constexpr int OA = 0, OA2 = 64 * 40, OW = 2 * 64 * 40, OW2 = 3 * 64 * 40;
  int bid = blockIdx.x;
  int r0 = (bid >> 2) * 64, c0 = (bid & 3) * 64;

  int t = threadIdx.x;
  int lane = t & 63, w = t >> 6;
  int l31 = lane & 31, half = lane >> 5;
  int wr = w >> 1, wc = w & 1;
  int rowA = t >> 2, kq = (t & 3) * 8;

  f32x16 acc;
#pragma unroll
  for (int i = 0; i < 16; ++i) acc[i] = 0.f;

  short8 ra, ra2;
  float4 rw0, rw1;
  auto prefetch = [&](int kc) {
    ra = *(const short8*)&A[(size_t)(r0 + rowA) * 256 + kc + kq];
    ra2 = *(const short8*)&A2[(size_t)(r0 + rowA) * 256 + kc + kq];
    const float* wp = &W[(size_t)(c0 + rowA) * 256 + kc + kq];
    rw0 = *(const float4*)wp;
    rw1 = *(const float4*)(wp + 4);
  };
  auto store = [&]() {
    *(short8*)&smem[OA + rowA * 40 + kq] = ra;
    *(short8*)&smem[OA2 + rowA * 40 + kq] = ra2;
    float vals[8] = {rw0.x, rw0.y, rw0.z, rw0.w, rw1.x, rw1.y, rw1.z, rw1.w};
    short8 hi, lo;
#pragma unroll
    for (int j = 0; j < 8; ++j) {
      hi[j] = (short)f2bf(vals[j]);
      lo[j] = (short)f2bf(vals[j] - bf2f((ushort)hi[j]));
    }
    *(short8*)&smem[OW + rowA * 40 + kq] = hi;
    *(short8*)&smem[OW2 + rowA * 40 + kq] = lo;
  };

  prefetch(0);
  store();
  __syncthreads();
  for (int i = 0; i < 8; ++i) {
    if (i < 7) prefetch((i + 1) * 32);
#pragma unroll
    for (int ks = 0; ks < 2; ++ks) {
      int ro = (wr * 32 + l31) * 40 + ks * 16 + half * 8;
      int co = (wc * 32 + l31) * 40 + ks * 16 + half * 8;
      short8 af = *(const short8*)&smem[OA + ro];
      short8 af2 = *(const short8*)&smem[OA2 + ro];
      short8 wf = *(const short8*)&smem[OW + co];
      short8 wf2 = *(const short8*)&smem[OW2 + co];
      acc = __builtin_amdgcn_mfma_f32_32x32x16_bf16(af, wf, acc, 0, 0, 0);
      acc = __builtin_amdgcn_mfma_f32_32x32x16_bf16(af2, wf, acc, 0, 0, 0);
      acc = __builtin_amdgcn_mfma_f32_32x32x16_bf16(af, wf2, acc, 0, 0, 0);
    }
    __syncthreads();
    if (i < 7) {
      store();
      __syncthreads();
    }
  }

#pragma unroll
  for (int i = 0; i < 16; ++i) {
    int rl = (i & 3) + 8 * (i >> 2) + 4 * half;
    int r = r0 + wr * 32 + rl;
    int c = c0 + wc * 32 + l31;
    out[(size_t)r * 256 + c] = acc[i] + bias[c];
  }
}

// ---------------------------------------------------------------------------
extern "C" void kernel_launch(void* const* d_in, const int* in_sizes, int n_in,
                              void* d_out, int out_size, void* d_ws, size_t ws_size,
                              hipStream_t stream) {
  const float* x      = (const float*)d_in[0];
  const float* dw_w   = (const float*)d_in[1];
  const float* dw_b   = (const float*)d_in[2];
  const float* pw_w   = (const float*)d_in[3];
  const float* pw_b   = (const float*)d_in[4];
  const float* sr_w   = (const float*)d_in[5];
  const float* ln_g   = (const float*)d_in[6];
  const float* ln_b   = (const float*)d_in[7];
  const float* kv_w   = (const float*)d_in[8];
  const float* kv_b   = (const float*)d_in[9];
  const float* proj_w = (const float*)d_in[10];
  const float* proj_b = (const float*)d_in[11];
  float* out = (float*)d_out;

  char* ws = (char*)d_ws;
  ushort* q1b = (ushort*)(ws);                  // 16384x256 bf16  (8 MB)
  ushort* xsr = (ushort*)(ws + (8u << 20));     // 4096x256        (2 MB)
  ushort* qB  = (ushort*)(ws + (16u << 20));    // 32x4096x32      (8 MB)
  ushort* kBp = (ushort*)(ws + (24u << 20));    // 32x1024x32      (2 MB)
  ushort* vTp = (ushort*)(ws + (26u << 20));    // 32x32x1024      (2 MB)
  ushort* aH  = (ushort*)(ws + (28u << 20));    // 16384x256       (8 MB)
  ushort* aL  = (ushort*)(ws + (36u << 20));    // 16384x256       (8 MB)

  pre_fused<<<dim3(4608), 256, 0, stream>>>(x, dw_w, dw_b, sr_w, ln_g, ln_b,
                                            q1b, xsr);
  gemm_qkv<<<dim3(1536), 256, 0, stream>>>(q1b, xsr, pw_w, pw_b, kv_w, kv_b,
                                           qB, kBp, vTp);
  attn_mfma<<<dim3(32, 32), 256, 0, stream>>>(qB, kBp, vTp, aH, aL);
  gemm_proj<<<dim3(1024), 256, 0, stream>>>(aH, aL, proj_w, proj_b, out);
}